// Round 6
// baseline (579.582 us; speedup 1.0000x reference)
//
#include <hip/hip_runtime.h>

// ---------------------------------------------------------------------------
// UnetMACReconNet: modulated-conv UNet + IN/ReLU + FFT data consistency
// Round 6: double-buffered LDS conv pipeline (1 barrier/chunk, loads in
//          flight under MFMA), VR=2 tiles for occupancy, all fusions kept.
// ---------------------------------------------------------------------------

#define EPS_IN 1e-5f

typedef __attribute__((ext_vector_type(8))) short short8;
typedef __attribute__((ext_vector_type(4))) short short4_t;
typedef __attribute__((ext_vector_type(4))) float f32x4;

__device__ __forceinline__ short f2bf(float f) {
    unsigned u = __float_as_uint(f);
    unsigned r = (u + 0x7fffu + ((u >> 16) & 1u)) >> 16;
    return (short)r;
}
__device__ __forceinline__ float bf2f(short s) {
    return __uint_as_float(((unsigned)(unsigned short)s) << 16);
}

// ---------------- zero the stat accumulators --------------------------------
__global__ void zero_f(float* __restrict__ p, int n)
{
    int i = blockIdx.x * 256 + threadIdx.x;
    if (i < n) p[i] = 0.f;
}

// ---------------- precompute modded bf16 weights: wm[b][tap][co][ci] --------
__global__ void make_wm(const float* __restrict__ W, const float* __restrict__ mod,
                        short* __restrict__ wm, int Co, int Ci)
{
    int idx = blockIdx.x * 256 + threadIdx.x;
    int total = 8 * Co * Ci;
    if (idx >= total) return;
    int ci = idx % Ci;
    int rem = idx / Ci;
    int co = rem % Co;
    int b = rem / Co;
    const float* wp = W + (size_t)(co * Ci + ci) * 9;
    const float* mp = mod + ((size_t)((size_t)b * Co + co) * Ci + ci) * 9;
#pragma unroll
    for (int k = 0; k < 9; ++k)
        wm[(((size_t)(b * 9 + k) * Co + co) * Ci + ci)] = f2bf(wp[k] * mp[k]);
}

// ---------------- MFMA conv3x3, CL, double-buffered, fused IN ---------------
// x1 pre-normalized; x2 = raw skip normalized during staging via st2*invHW2.
// Pipeline per 32-ci chunk: write regs->LDS[cur]; barrier; issue next loads;
// MFMA on LDS[cur].  One barrier per chunk; loads hide under MFMA.
template <int VR, int NCOG>
__global__ __launch_bounds__(256) void conv3x3_cl(
    const short* __restrict__ x1, int Ci1,
    const short* __restrict__ x2,
    const float2* __restrict__ st2, float invHW2,
    const short* __restrict__ wm,   // [b][9][Co][Ci] bf16
    short* __restrict__ y,
    float2* __restrict__ stats,
    int Ci, int Co, int H, int W)
{
    constexpr int TH = 4 * VR, SH = TH + 2, SW = 18;
    constexpr int NPOS = SH * SW * 4;
    constexpr int NST = (NPOS + 255) / 256;
    __shared__ short s_x[2][SH][SW][32];
    __shared__ float s_red[4][4][NCOG][4][2];
    __shared__ float2 s_st[256];

    const int tid = threadIdx.x;
    const int lane = tid & 63, wv = tid >> 6;
    const int m = lane & 15, g = lane >> 4;
    const int tilesx = W >> 4;
    const int tx0 = (blockIdx.x % tilesx) * 16;
    const int ty0 = (blockIdx.x / tilesx) * TH;
    const int co0 = blockIdx.y * (16 * NCOG);
    const int b = blockIdx.z;
    const int Ci2 = Ci - Ci1;

    // normalized (mu, rsig) for the skip channels (used from chunk >= Ci1/32,
    // i.e. always after the first barrier)
    for (int i = tid; i < Ci2; i += 256) {
        float2 v = st2[(size_t)b * Ci2 + i];
        float mu = v.x * invHW2;
        float var = v.y * invHW2 - mu * mu;
        s_st[i] = make_float2(mu, rsqrtf(var + EPS_IN));
    }

    // per-thread staging geometry (constant across chunks)
    int p_yy[NST], p_xx[NST], p_gg[NST];
    bool p_inb[NST];
    size_t p_off[NST];   // (gy*W+gx), valid when inb
#pragma unroll
    for (int it = 0; it < NST; ++it) {
        int idx = tid + it * 256;
        int gg = idx & 3, pos = idx >> 2;
        int yy = pos / SW, xx = pos - yy * SW;
        p_yy[it] = yy; p_xx[it] = xx; p_gg[it] = gg;
        int gy = ty0 + yy - 1, gx = tx0 + xx - 1;
        bool inb = (idx < NPOS) && gy >= 0 && gy < H && gx >= 0 && gx < W;
        p_inb[it] = inb;
        p_off[it] = (size_t)gy * W + gx;
    }

    f32x4 acc[NCOG][VR];
#pragma unroll
    for (int cg = 0; cg < NCOG; ++cg)
#pragma unroll
        for (int r = 0; r < VR; ++r) acc[cg][r] = (f32x4)0.f;

    const short* wmb = wm + (size_t)b * 9 * Co * Ci;
    const short* x1b = x1 + (size_t)b * H * W * Ci1;
    const short* x2b = x2 + (size_t)b * H * W * Ci2;

    short8 stg[NST];
    auto load_chunk = [&](int ci0) {
        const short* src; int C, cb;
        if (ci0 < Ci1) { src = x1b; C = Ci1; cb = ci0; }
        else           { src = x2b; C = Ci2; cb = ci0 - Ci1; }
#pragma unroll
        for (int it = 0; it < NST; ++it) {
            short8 v = (short8)0;
            if (p_inb[it])
                v = *(const short8*)(src + p_off[it] * C + cb + p_gg[it] * 8);
            stg[it] = v;
        }
    };

    load_chunk(0);
    int cur = 0;

    for (int ci0 = 0; ci0 < Ci; ci0 += 32) {
        // ---- write staged regs -> LDS[cur] (normalize skip channels)
        const bool nrm = (ci0 >= Ci1);
        const int cb = nrm ? (ci0 - Ci1) : ci0;
#pragma unroll
        for (int it = 0; it < NST; ++it) {
            if (tid + it * 256 < NPOS) {
                short8 v = stg[it];
                if (nrm && p_inb[it]) {
#pragma unroll
                    for (int e = 0; e < 8; ++e) {
                        float2 s = s_st[cb + p_gg[it] * 8 + e];
                        v[e] = f2bf(fmaxf(0.f, (bf2f(v[e]) - s.x) * s.y));
                    }
                }
                *(short8*)&s_x[cur][p_yy[it]][p_xx[it]][(p_gg[it] ^ (p_xx[it] & 3)) * 8] = v;
            }
        }
        __syncthreads();
        if (ci0 + 32 < Ci) load_chunk(ci0 + 32);   // in flight under MFMA

        // ---- 9 taps, K=32 each
#pragma unroll
        for (int t = 0; t < 9; ++t) {
            const int dy = t / 3, dx = t - 3 * (t / 3);
            const short* wr = wmb + ((size_t)t * Co + co0) * Ci + ci0 + g * 8;
            short8 a[NCOG];
#pragma unroll
            for (int cg = 0; cg < NCOG; ++cg)
                a[cg] = *(const short8*)(wr + (size_t)(cg * 16 + m) * Ci);
            const int xx = m + dx;
            const int sgo = (g ^ (xx & 3)) * 8;
#pragma unroll
            for (int r = 0; r < VR; ++r) {
                short8 bf = *(const short8*)&s_x[cur][wv * VR + r + dy][xx][sgo];
#pragma unroll
                for (int cg = 0; cg < NCOG; ++cg)
                    acc[cg][r] = __builtin_amdgcn_mfma_f32_16x16x32_bf16(a[cg], bf, acc[cg][r], 0, 0, 0);
            }
        }
        cur ^= 1;
    }

    // ---- writeout (CL: 4 consecutive co per lane) + fused stats
    const int ox = tx0 + m;
#pragma unroll
    for (int cg = 0; cg < NCOG; ++cg)
#pragma unroll
        for (int r = 0; r < VR; ++r) {
            int oy = ty0 + wv * VR + r;
            short4_t o;
#pragma unroll
            for (int q = 0; q < 4; ++q) o[q] = f2bf(acc[cg][r][q]);
            *(short4_t*)(y + (((size_t)b * H + oy) * W + ox) * Co + co0 + cg * 16 + g * 4) = o;
        }

#pragma unroll
    for (int cg = 0; cg < NCOG; ++cg)
#pragma unroll
        for (int q = 0; q < 4; ++q) {
            float s = 0.f, s2 = 0.f;
#pragma unroll
            for (int r = 0; r < VR; ++r) { float v = acc[cg][r][q]; s += v; s2 += v * v; }
#pragma unroll
            for (int msk = 1; msk < 16; msk <<= 1) { s += __shfl_xor(s, msk); s2 += __shfl_xor(s2, msk); }
            if (m == 0) { s_red[wv][g][cg][q][0] = s; s_red[wv][g][cg][q][1] = s2; }
        }
    __syncthreads();
    for (int i = tid; i < 16 * NCOG; i += 256) {
        int q = i & 3, gg = (i >> 2) & 3, cg = i >> 4;
        float S = 0.f, S2 = 0.f;
#pragma unroll
        for (int w = 0; w < 4; ++w) { S += s_red[w][gg][cg][q][0]; S2 += s_red[w][gg][cg][q][1]; }
        float* sp = (float*)&stats[(size_t)b * Co + co0 + i];
        atomicAdd(sp, S); atomicAdd(sp + 1, S2);
    }
}

// ---------------- d0 conv: Ci=1, Co=32, fp32 NCHW in -> CL bf16 raw out -----
__global__ __launch_bounds__(256) void conv_d0_cl(
    const float* __restrict__ x0, const float* __restrict__ W,
    const float* __restrict__ mod, short* __restrict__ y,
    float2* __restrict__ stats)
{
    __shared__ float s[18][18];
    __shared__ float sw[32][9];
    __shared__ float s_red[4][32][2];
    const int tid = threadIdx.x;
    const int tx = tid & 15, ty = tid >> 4;
    const int tx0 = (blockIdx.x & 15) * 16, ty0 = (blockIdx.x >> 4) * 16;
    const int b = blockIdx.y;
    if (tid < 288) sw[tid / 9][tid % 9] = W[tid] * mod[b * 288 + tid];
    for (int pos = tid; pos < 18 * 18; pos += 256) {
        int yy = pos / 18, xx = pos - yy * 18;
        int gy = ty0 + yy - 1, gx = tx0 + xx - 1;
        bool inb = gy >= 0 && gy < 256 && gx >= 0 && gx < 256;
        s[yy][xx] = inb ? x0[((size_t)b << 16) + gy * 256 + gx] : 0.f;
    }
    __syncthreads();
    float v[3][3];
#pragma unroll
    for (int r = 0; r < 3; ++r)
#pragma unroll
        for (int c = 0; c < 3; ++c) v[r][c] = s[ty + r][tx + c];
    float vals[32];
#pragma unroll
    for (int co = 0; co < 32; ++co) {
        float a = 0.f;
#pragma unroll
        for (int r = 0; r < 3; ++r)
#pragma unroll
            for (int c = 0; c < 3; ++c) a = fmaf(v[r][c], sw[co][r * 3 + c], a);
        vals[co] = a;
    }
    short* yp = y + (((size_t)b * 256 + ty0 + ty) * 256 + tx0 + tx) * 32;
#pragma unroll
    for (int j = 0; j < 4; ++j) {
        short8 o;
#pragma unroll
        for (int e = 0; e < 8; ++e) o[e] = f2bf(vals[j * 8 + e]);
        *(short8*)(yp + j * 8) = o;
    }
    const int lane = tid & 63, wv = tid >> 6;
#pragma unroll
    for (int co = 0; co < 32; ++co) {
        float sm = vals[co], s2 = vals[co] * vals[co];
#pragma unroll
        for (int off = 32; off > 0; off >>= 1) { sm += __shfl_down(sm, off); s2 += __shfl_down(s2, off); }
        if (lane == 0) { s_red[wv][co][0] = sm; s_red[wv][co][1] = s2; }
    }
    __syncthreads();
    if (tid < 32) {
        float S = 0.f, S2 = 0.f;
#pragma unroll
        for (int w = 0; w < 4; ++w) { S += s_red[w][tid][0]; S2 += s_red[w][tid][1]; }
        float* sp = (float*)&stats[(size_t)b * 32 + tid];
        atomicAdd(sp, S); atomicAdd(sp + 1, S2);
    }
}

// ---------------- 2x2 maxpool + fused norm/relu (monotone => exact) ---------
__global__ void maxpool_cl(const short* __restrict__ in,
                           const float2* __restrict__ st, float invHW,
                           short* __restrict__ out,
                           int c8s, int ws, int hs, int total8)
{
    const int C = 8 << c8s;
    for (int idx = blockIdx.x * 256 + threadIdx.x; idx < total8; idx += gridDim.x * 256) {
        int c8 = idx & ((1 << c8s) - 1);
        int p = idx >> c8s;
        int x = p & ((1 << ws) - 1);
        int yy = (p >> ws) & ((1 << hs) - 1);
        int b = p >> (ws + hs);
        const short* ip = in + (((size_t)b * (2 << hs) + 2 * yy) * (2 << ws) + 2 * x) * C + c8 * 8;
        size_t rs = (size_t)(2 << ws) * C;
        short8 v0 = *(const short8*)ip, v1 = *(const short8*)(ip + C);
        short8 v2 = *(const short8*)(ip + rs), v3 = *(const short8*)(ip + rs + C);
        short8 o;
#pragma unroll
        for (int e = 0; e < 8; ++e) {
            float mx = fmaxf(fmaxf(bf2f(v0[e]), bf2f(v1[e])), fmaxf(bf2f(v2[e]), bf2f(v3[e])));
            float2 sv = st[(size_t)b * C + c8 * 8 + e];
            float mu = sv.x * invHW;
            float rsig = rsqrtf(sv.y * invHW - mu * mu + EPS_IN);
            o[e] = f2bf(fmaxf(0.f, (mx - mu) * rsig));
        }
        *(short8*)(out + (size_t)idx * 8) = o;
    }
}

// ---------------- bilinear 2x upsample + fused norm/relu (pre-lerp) ---------
__global__ void upsample_cl(const short* __restrict__ in,
                            const float2* __restrict__ st, float invHW,
                            short* __restrict__ out,
                            int c8s, int wsi, int hsi, int total8)
{
    const int C = 8 << c8s;
    const int Win = 1 << wsi, Hin = 1 << hsi;
    for (int idx = blockIdx.x * 256 + threadIdx.x; idx < total8; idx += gridDim.x * 256) {
        int c8 = idx & ((1 << c8s) - 1);
        int p = idx >> c8s;
        int x = p & (2 * Win - 1);
        int yy = (p >> (wsi + 1)) & (2 * Hin - 1);
        int b = p >> (wsi + 1 + hsi + 1);
        int xk = x >> 1, yk = yy >> 1;
        int xa, xb; float wxa;
        if (x & 1) { xa = xk; xb = (xk + 1 < Win) ? xk + 1 : Win - 1; wxa = 0.75f; }
        else       { xa = (xk > 0) ? xk - 1 : 0; xb = xk; wxa = 0.25f; }
        int ya, yb; float wya;
        if (yy & 1) { ya = yk; yb = (yk + 1 < Hin) ? yk + 1 : Hin - 1; wya = 0.75f; }
        else        { ya = (yk > 0) ? yk - 1 : 0; yb = yk; wya = 0.25f; }
        const short* ib = in + (size_t)b * Hin * Win * C + c8 * 8;
        short8 vaa = *(const short8*)(ib + ((size_t)ya * Win + xa) * C);
        short8 vab = *(const short8*)(ib + ((size_t)ya * Win + xb) * C);
        short8 vba = *(const short8*)(ib + ((size_t)yb * Win + xa) * C);
        short8 vbb = *(const short8*)(ib + ((size_t)yb * Win + xb) * C);
        short8 o;
#pragma unroll
        for (int e = 0; e < 8; ++e) {
            float2 sv = st[(size_t)b * C + c8 * 8 + e];
            float mu = sv.x * invHW;
            float rsig = rsqrtf(sv.y * invHW - mu * mu + EPS_IN);
            float aa = fmaxf(0.f, (bf2f(vaa[e]) - mu) * rsig);
            float ab = fmaxf(0.f, (bf2f(vab[e]) - mu) * rsig);
            float ba = fmaxf(0.f, (bf2f(vba[e]) - mu) * rsig);
            float bb = fmaxf(0.f, (bf2f(vbb[e]) - mu) * rsig);
            float r0 = wxa * aa + (1.f - wxa) * ab;
            float r1 = wxa * ba + (1.f - wxa) * bb;
            o[e] = f2bf(wya * r0 + (1.f - wya) * r1);
        }
        *(short8*)(out + (size_t)idx * 8) = o;
    }
}

// ---------------- compose the three 1x1 convs into one 32->1 map ------------
__global__ void eff1x1(const float* __restrict__ w1, const float* __restrict__ b1,
                       const float* __restrict__ w2, const float* __restrict__ b2,
                       const float* __restrict__ w3, const float* __restrict__ b3,
                       float* __restrict__ eff)
{
    int t = threadIdx.x;
    if (t < 32) {
        float s = 0.f;
        for (int k = 0; k < 16; ++k) s += w2[k] * w1[k * 32 + t];
        eff[t] = w3[0] * s;
    }
    if (t == 32) {
        float s = 0.f;
        for (int k = 0; k < 16; ++k) s += w2[k] * b1[k];
        eff[32] = w3[0] * (s + b2[0]) + b3[0];
    }
}

// ---------------- final: norm/relu(u3) -> 32->1 conv + residual -------------
__global__ __launch_bounds__(256) void final_pred_cl(
    const short* __restrict__ act, const float2* __restrict__ st, float invHW,
    const float* __restrict__ x0, const float* __restrict__ eff,
    float* __restrict__ pred)
{
    __shared__ float2 s_st[32];
    int idx = blockIdx.x * 256 + threadIdx.x;  // exactly B*65536 threads
    int b = idx >> 16;
    if (threadIdx.x < 32) {
        float2 v = st[(size_t)b * 32 + threadIdx.x];
        float mu = v.x * invHW;
        s_st[threadIdx.x] = make_float2(mu, rsqrtf(v.y * invHW - mu * mu + EPS_IN));
    }
    __syncthreads();
    const short8* a = (const short8*)(act + (size_t)idx * 32);
    float s = eff[32] + x0[idx];
#pragma unroll
    for (int j = 0; j < 4; ++j) {
        short8 v = a[j];
#pragma unroll
        for (int e = 0; e < 8; ++e) {
            float2 sv = s_st[j * 8 + e];
            float f = fmaxf(0.f, (bf2f(v[e]) - sv.x) * sv.y);
            s += eff[j * 8 + e] * f;
        }
    }
    pred[idx] = s;
}

// ---------------- 256-point radix-2 FFT in LDS (one wave) -------------------
__device__ __forceinline__ void fft256(float2* s, int tid, float sign)
{
    __syncthreads();
#pragma unroll
    for (int t = 0; t < 4; ++t) {
        int i = tid + t * 64;
        int r = __brev(i) >> 24;
        if (r > i) { float2 tmp = s[i]; s[i] = s[r]; s[r] = tmp; }
    }
    __syncthreads();
    for (int st = 1; st <= 8; ++st) {
        int m = 1 << st, half = m >> 1;
#pragma unroll
        for (int t = 0; t < 2; ++t) {
            int k = tid + t * 64;
            int g = k >> (st - 1), j = k & (half - 1);
            int i0 = (g << st) + j, i1 = i0 + half;
            float ang = sign * 6.283185307179586f * (float)j / (float)m;
            float sn, cs;
            __sincosf(ang, &sn, &cs);
            float2 a = s[i0], b = s[i1];
            float2 tt = make_float2(b.x * cs - b.y * sn, b.x * sn + b.y * cs);
            s[i0] = make_float2(a.x + tt.x, a.y + tt.y);
            s[i1] = make_float2(a.x - tt.x, a.y - tt.y);
        }
        __syncthreads();
    }
}

__global__ __launch_bounds__(64) void fft_rows_fwd(const float* __restrict__ pred,
                                                   float2* __restrict__ out)
{
    __shared__ float2 s[256];
    int row = blockIdx.x, tid = threadIdx.x;
    const float* p = pred + (size_t)row * 256;
    for (int i = tid; i < 256; i += 64) s[i] = make_float2(p[i], 0.f);
    fft256(s, tid, -1.f);
    float2* o = out + (size_t)row * 256;
    for (int i = tid; i < 256; i += 64) o[i] = s[i];
}

__global__ __launch_bounds__(64) void fft_cols_combine(float2* __restrict__ data,
                                                       const float* __restrict__ ksp,
                                                       const float* __restrict__ mask)
{
    __shared__ float2 s[256];
    int col = blockIdx.x & 255, b = blockIdx.x >> 8;
    int tid = threadIdx.x;
    float2* base = data + (size_t)b * 65536 + col;
    for (int i = tid; i < 256; i += 64) s[i] = base[(size_t)i * 256];
    fft256(s, tid, -1.f);
    for (int i = tid; i < 256; i += 64) {
        size_t mi = ((size_t)b * 256 + i) * 256 + col;
        float m = mask[mi];
        float2 kp = s[i];
        float kr = ksp[mi * 2], ki = ksp[mi * 2 + 1];
        s[i] = make_float2(m * kr + (1.f - m) * kp.x * (1.f / 256.f),
                           m * ki + (1.f - m) * kp.y * (1.f / 256.f));
    }
    fft256(s, tid, 1.f);
    for (int i = tid; i < 256; i += 64) base[(size_t)i * 256] = s[i];
}

__global__ __launch_bounds__(64) void fft_rows_inv(const float2* __restrict__ data,
                                                   float* __restrict__ out)
{
    __shared__ float2 s[256];
    int row = blockIdx.x, tid = threadIdx.x;
    const float2* p = data + (size_t)row * 256;
    for (int i = tid; i < 256; i += 64) s[i] = p[i];
    fft256(s, tid, 1.f);
    float* o = out + (size_t)row * 256;
    for (int i = tid; i < 256; i += 64) o[i] = s[i].x * (1.f / 256.f);
}

// ---------------------------------------------------------------------------
extern "C" void kernel_launch(void* const* d_in, const int* in_sizes, int n_in,
                              void* d_out, int out_size, void* d_ws, size_t ws_size,
                              hipStream_t stream)
{
    (void)in_sizes; (void)n_in; (void)out_size; (void)ws_size;

    const float* x0 = (const float*)d_in[0];
    const float* ksp = (const float*)d_in[1];
    const float* mask = (const float*)d_in[2];
    const float* mod_d[4] = {(const float*)d_in[3], (const float*)d_in[6],
                             (const float*)d_in[9], (const float*)d_in[12]};
    const float* W_d[4] = {(const float*)d_in[4], (const float*)d_in[7],
                           (const float*)d_in[10], (const float*)d_in[13]};
    const float* mod_lat = (const float*)d_in[15];
    const float* W_lat = (const float*)d_in[16];
    const float* mod_u[4] = {(const float*)d_in[18], (const float*)d_in[21],
                             (const float*)d_in[24], (const float*)d_in[27]};
    const float* W_u[4] = {(const float*)d_in[19], (const float*)d_in[22],
                           (const float*)d_in[25], (const float*)d_in[28]};
    const float* w_c1 = (const float*)d_in[30];
    const float* b_c1 = (const float*)d_in[31];
    const float* w_c2 = (const float*)d_in[32];
    const float* b_c2 = (const float*)d_in[33];
    const float* w_c3 = (const float*)d_in[34];
    const float* b_c3 = (const float*)d_in[35];

    // ---- workspace layout (CL bf16 activations), ~146 MB
    short* sA  = (short*)d_ws;          // 16,777,216
    short* sB  = sA + 16777216;         // 16,777,216
    short* sk0 = sB + 16777216;         // 16,777,216 (8,256,256,32) raw
    short* sk1 = sk0 + 16777216;        //  8,388,608 (8,128,128,64) raw
    short* sk2 = sk1 + 8388608;         //  4,194,304 (8,64,64,128) raw
    short* sk3 = sk2 + 4194304;         //  2,097,152 (8,32,32,256) raw
    short* wm  = sk3 + 2097152;         //  4,718,592 (JIT wm scratch)
    float* pred = (float*)(wm + 4718592);      // 524,288
    float2* cplx = (float2*)(pred + 524288);   // 524,288 float2
    float2* stA = cplx + 524288;               // 7,936 float2 stat accumulators
    float* eff = (float*)(stA + 7936);         // 64

    // per-layer stat slices
    float2* st_d0 = stA + 0;
    float2* st_d1 = stA + 256;
    float2* st_d2 = stA + 768;
    float2* st_d3 = stA + 1792;
    float2* st_lat = stA + 3840;
    float2* st_u0 = stA + 5888;
    float2* st_u1 = stA + 6912;
    float2* st_u2 = stA + 7424;
    float2* st_u3 = stA + 7680;

    const float i64k = 1.f / 65536.f, i16k = 1.f / 16384.f, i4k = 1.f / 4096.f,
                i1k = 1.f / 1024.f, i256 = 1.f / 256.f;

    dim3 blk(256);

    zero_f<<<62, blk, 0, stream>>>((float*)stA, 15872);
    eff1x1<<<1, 64, 0, stream>>>(w_c1, b_c1, w_c2, b_c2, w_c3, b_c3, eff);

    // ---- down 0: 1 -> 32 @256 (raw out + stats)
    conv_d0_cl<<<dim3(256, 8), blk, 0, stream>>>(x0, W_d[0], mod_d[0], sk0, st_d0);
    maxpool_cl<<<2048, blk, 0, stream>>>(sk0, st_d0, i64k, sA, 2, 7, 7, 524288);

    // ---- down 1: 32 -> 64 @128  (1 chunk)
    make_wm<<<(8 * 64 * 32 + 255) / 256, blk, 0, stream>>>(W_d[1], mod_d[1], wm, 64, 32);
    conv3x3_cl<2, 4><<<dim3(128, 1, 8), blk, 0, stream>>>(sA, 32, sA, stA, 0.f, wm, sk1, st_d1, 32, 64, 128, 128);
    maxpool_cl<<<1024, blk, 0, stream>>>(sk1, st_d1, i16k, sA, 3, 6, 6, 262144);

    // ---- down 2: 64 -> 128 @64  (2 chunks)
    make_wm<<<(8 * 128 * 64 + 255) / 256, blk, 0, stream>>>(W_d[2], mod_d[2], wm, 128, 64);
    conv3x3_cl<2, 4><<<dim3(32, 2, 8), blk, 0, stream>>>(sA, 64, sA, stA, 0.f, wm, sk2, st_d2, 64, 128, 64, 64);
    maxpool_cl<<<512, blk, 0, stream>>>(sk2, st_d2, i4k, sA, 4, 5, 5, 131072);

    // ---- down 3: 128 -> 256 @32 (4 chunks)
    make_wm<<<(8 * 256 * 128 + 255) / 256, blk, 0, stream>>>(W_d[3], mod_d[3], wm, 256, 128);
    conv3x3_cl<2, 2><<<dim3(8, 8, 8), blk, 0, stream>>>(sA, 128, sA, stA, 0.f, wm, sk3, st_d3, 128, 256, 32, 32);
    maxpool_cl<<<256, blk, 0, stream>>>(sk3, st_d3, i1k, sA, 5, 4, 4, 65536);

    // ---- latent: 256 -> 256 @16 (8 chunks)
    make_wm<<<(8 * 256 * 256 + 255) / 256, blk, 0, stream>>>(W_lat, mod_lat, wm, 256, 256);
    conv3x3_cl<1, 1><<<dim3(4, 16, 8), blk, 0, stream>>>(sA, 256, sA, stA, 0.f, wm, sB, st_lat, 256, 256, 16, 16);

    // ---- up 0: up(norm(lat)@16->32) ++ norm(sk3) -> 128 @32 (16 chunks)
    upsample_cl<<<1024, blk, 0, stream>>>(sB, st_lat, i256, sA, 5, 4, 4, 262144);
    make_wm<<<(8 * 128 * 512 + 255) / 256, blk, 0, stream>>>(W_u[0], mod_u[0], wm, 128, 512);
    conv3x3_cl<2, 1><<<dim3(8, 8, 8), blk, 0, stream>>>(sA, 256, sk3, st_d3, i1k, wm, sB, st_u0, 512, 128, 32, 32);

    // ---- up 1: up(norm(u0)@32->64) ++ norm(sk2) -> 64 @64 (8 chunks)
    upsample_cl<<<2048, blk, 0, stream>>>(sB, st_u0, i1k, sA, 4, 5, 5, 524288);
    make_wm<<<(8 * 64 * 256 + 255) / 256, blk, 0, stream>>>(W_u[1], mod_u[1], wm, 64, 256);
    conv3x3_cl<2, 2><<<dim3(32, 2, 8), blk, 0, stream>>>(sA, 128, sk2, st_d2, i4k, wm, sB, st_u1, 256, 64, 64, 64);

    // ---- up 2: up(norm(u1)@64->128) ++ norm(sk1) -> 32 @128 (4 chunks)
    upsample_cl<<<4096, blk, 0, stream>>>(sB, st_u1, i4k, sA, 3, 6, 6, 1048576);
    make_wm<<<(8 * 32 * 128 + 255) / 256, blk, 0, stream>>>(W_u[2], mod_u[2], wm, 32, 128);
    conv3x3_cl<2, 2><<<dim3(128, 1, 8), blk, 0, stream>>>(sA, 64, sk1, st_d1, i16k, wm, sB, st_u2, 128, 32, 128, 128);

    // ---- up 3: up(norm(u2)@128->256) ++ norm(sk0) -> 32 @256 (2 chunks)
    upsample_cl<<<8192, blk, 0, stream>>>(sB, st_u2, i16k, sA, 2, 7, 7, 2097152);
    make_wm<<<(8 * 32 * 64 + 255) / 256, blk, 0, stream>>>(W_u[3], mod_u[3], wm, 32, 64);
    conv3x3_cl<2, 2><<<dim3(512, 1, 8), blk, 0, stream>>>(sA, 32, sk0, st_d0, i64k, wm, sB, st_u3, 64, 32, 256, 256);

    // ---- fused norm(u3) + 1x1 chain + residual
    final_pred_cl<<<2048, blk, 0, stream>>>(sB, st_u3, i64k, x0, eff, pred);

    // ---- FFT data consistency
    fft_rows_fwd<<<2048, 64, 0, stream>>>(pred, cplx);
    fft_cols_combine<<<2048, 64, 0, stream>>>(cplx, ksp, mask);
    fft_rows_inv<<<2048, 64, 0, stream>>>(cplx, (float*)d_out);
}

// Round 7
// 518.270 us; speedup vs baseline: 1.1183x; 1.1183x over previous
//
#include <hip/hip_runtime.h>

// ---------------------------------------------------------------------------
// UnetMACReconNet: modulated-conv UNet + IN/ReLU + FFT data consistency
// Round 7: conv reverted to the measured-best R4 structure (lean, 52 VGPR);
//          norm/relu fused into pool (with in-place normalized skip
//          writeback), upsample, and final_pred. No standalone norm passes.
// ---------------------------------------------------------------------------

#define EPS_IN 1e-5f

typedef __attribute__((ext_vector_type(8))) short short8;
typedef __attribute__((ext_vector_type(4))) short short4_t;
typedef __attribute__((ext_vector_type(4))) float f32x4;

__device__ __forceinline__ short f2bf(float f) {
    unsigned u = __float_as_uint(f);
    unsigned r = (u + 0x7fffu + ((u >> 16) & 1u)) >> 16;
    return (short)r;
}
__device__ __forceinline__ float bf2f(short s) {
    return __uint_as_float(((unsigned)(unsigned short)s) << 16);
}

// ---------------- zero the stat accumulators --------------------------------
__global__ void zero_f(float* __restrict__ p, int n)
{
    int i = blockIdx.x * 256 + threadIdx.x;
    if (i < n) p[i] = 0.f;
}

// ---------------- precompute modded bf16 weights: wm[b][tap][co][ci] --------
__global__ void make_wm(const float* __restrict__ W, const float* __restrict__ mod,
                        short* __restrict__ wm, int Co, int Ci)
{
    int idx = blockIdx.x * 256 + threadIdx.x;
    int total = 8 * Co * Ci;
    if (idx >= total) return;
    int ci = idx % Ci;
    int rem = idx / Ci;
    int co = rem % Co;
    int b = rem / Co;
    const float* wp = W + (size_t)(co * Ci + ci) * 9;
    const float* mp = mod + ((size_t)((size_t)b * Co + co) * Ci + ci) * 9;
#pragma unroll
    for (int k = 0; k < 9; ++k)
        wm[(((size_t)(b * 9 + k) * Co + co) * Ci + ci)] = f2bf(wp[k] * mp[k]);
}

// ---------------- MFMA conv3x3, channels-last, fused IN-stat accumulation ---
// (R4 structure: single LDS buffer, direct global->LDS staging loop.)
// Inputs x1/x2 are both already normalized. Output raw + stats atomics.
template <int VR, int NCOG>
__global__ __launch_bounds__(256) void conv3x3_cl(
    const short* __restrict__ x1, int Ci1,
    const short* __restrict__ x2,
    const short* __restrict__ wm,   // [b][9][Co][Ci] bf16
    short* __restrict__ y,
    float2* __restrict__ stats,
    int Ci, int Co, int H, int W)
{
    constexpr int TH = 4 * VR, SH = TH + 2, SW = 18;
    __shared__ short s_x[SH][SW][32];
    __shared__ float s_red[4][4][NCOG][4][2];

    const int tid = threadIdx.x;
    const int lane = tid & 63, wv = tid >> 6;
    const int m = lane & 15, g = lane >> 4;
    const int tilesx = W >> 4;
    const int tx0 = (blockIdx.x % tilesx) * 16;
    const int ty0 = (blockIdx.x / tilesx) * TH;
    const int co0 = blockIdx.y * (16 * NCOG);
    const int b = blockIdx.z;
    const int Ci2 = Ci - Ci1;

    f32x4 acc[NCOG][VR];
#pragma unroll
    for (int cg = 0; cg < NCOG; ++cg)
#pragma unroll
        for (int r = 0; r < VR; ++r) acc[cg][r] = (f32x4)0.f;

    const short* wmb = wm + (size_t)b * 9 * Co * Ci;

    for (int ci0 = 0; ci0 < Ci; ci0 += 32) {
        const short* src; int C, cb;
        if (ci0 < Ci1) { src = x1 + (size_t)b * H * W * Ci1; C = Ci1; cb = ci0; }
        else           { src = x2 + (size_t)b * H * W * Ci2; C = Ci2; cb = ci0 - Ci1; }
        __syncthreads();
        for (int idx = tid; idx < SH * SW * 4; idx += 256) {
            int gg = idx & 3, pos = idx >> 2;
            int yy = pos / SW, xx = pos - yy * SW;
            int gy = ty0 + yy - 1, gx = tx0 + xx - 1;
            short8 v = (short8)0;
            if (gy >= 0 && gy < H && gx >= 0 && gx < W)
                v = *(const short8*)(src + ((size_t)gy * W + gx) * C + cb + gg * 8);
            *(short8*)&s_x[yy][xx][(gg ^ (xx & 3)) * 8] = v;
        }
        __syncthreads();
#pragma unroll
        for (int t = 0; t < 9; ++t) {
            const int dy = t / 3, dx = t - 3 * (t / 3);
            const short* wr = wmb + ((size_t)t * Co + co0) * Ci + ci0 + g * 8;
            short8 a[NCOG];
#pragma unroll
            for (int cg = 0; cg < NCOG; ++cg)
                a[cg] = *(const short8*)(wr + (size_t)(cg * 16 + m) * Ci);
            const int xx = m + dx;
            const int sgo = (g ^ (xx & 3)) * 8;
#pragma unroll
            for (int r = 0; r < VR; ++r) {
                short8 bf = *(const short8*)&s_x[wv * VR + r + dy][xx][sgo];
#pragma unroll
                for (int cg = 0; cg < NCOG; ++cg)
                    acc[cg][r] = __builtin_amdgcn_mfma_f32_16x16x32_bf16(a[cg], bf, acc[cg][r], 0, 0, 0);
            }
        }
    }

    // ---- writeout (CL: 4 consecutive co per lane) + fused stats
    const int ox = tx0 + m;
#pragma unroll
    for (int cg = 0; cg < NCOG; ++cg)
#pragma unroll
        for (int r = 0; r < VR; ++r) {
            int oy = ty0 + wv * VR + r;
            short4_t o;
#pragma unroll
            for (int q = 0; q < 4; ++q) o[q] = f2bf(acc[cg][r][q]);
            *(short4_t*)(y + (((size_t)b * H + oy) * W + ox) * Co + co0 + cg * 16 + g * 4) = o;
        }

#pragma unroll
    for (int cg = 0; cg < NCOG; ++cg)
#pragma unroll
        for (int q = 0; q < 4; ++q) {
            float s = 0.f, s2 = 0.f;
#pragma unroll
            for (int r = 0; r < VR; ++r) { float v = acc[cg][r][q]; s += v; s2 += v * v; }
#pragma unroll
            for (int msk = 1; msk < 16; msk <<= 1) { s += __shfl_xor(s, msk); s2 += __shfl_xor(s2, msk); }
            if (m == 0) { s_red[wv][g][cg][q][0] = s; s_red[wv][g][cg][q][1] = s2; }
        }
    __syncthreads();
    for (int i = tid; i < 16 * NCOG; i += 256) {
        int q = i & 3, gg = (i >> 2) & 3, cg = i >> 4;
        float S = 0.f, S2 = 0.f;
#pragma unroll
        for (int w = 0; w < 4; ++w) { S += s_red[w][gg][cg][q][0]; S2 += s_red[w][gg][cg][q][1]; }
        float* sp = (float*)&stats[(size_t)b * Co + co0 + i];
        atomicAdd(sp, S); atomicAdd(sp + 1, S2);
    }
}

// ---------------- d0 conv: Ci=1, Co=32, fp32 NCHW in -> CL bf16 raw out -----
__global__ __launch_bounds__(256) void conv_d0_cl(
    const float* __restrict__ x0, const float* __restrict__ W,
    const float* __restrict__ mod, short* __restrict__ y,
    float2* __restrict__ stats)
{
    __shared__ float s[18][18];
    __shared__ float sw[32][9];
    __shared__ float s_red[4][32][2];
    const int tid = threadIdx.x;
    const int tx = tid & 15, ty = tid >> 4;
    const int tx0 = (blockIdx.x & 15) * 16, ty0 = (blockIdx.x >> 4) * 16;
    const int b = blockIdx.y;
    if (tid < 288) sw[tid / 9][tid % 9] = W[tid] * mod[b * 288 + tid];
    for (int pos = tid; pos < 18 * 18; pos += 256) {
        int yy = pos / 18, xx = pos - yy * 18;
        int gy = ty0 + yy - 1, gx = tx0 + xx - 1;
        bool inb = gy >= 0 && gy < 256 && gx >= 0 && gx < 256;
        s[yy][xx] = inb ? x0[((size_t)b << 16) + gy * 256 + gx] : 0.f;
    }
    __syncthreads();
    float v[3][3];
#pragma unroll
    for (int r = 0; r < 3; ++r)
#pragma unroll
        for (int c = 0; c < 3; ++c) v[r][c] = s[ty + r][tx + c];
    float vals[32];
#pragma unroll
    for (int co = 0; co < 32; ++co) {
        float a = 0.f;
#pragma unroll
        for (int r = 0; r < 3; ++r)
#pragma unroll
            for (int c = 0; c < 3; ++c) a = fmaf(v[r][c], sw[co][r * 3 + c], a);
        vals[co] = a;
    }
    short* yp = y + (((size_t)b * 256 + ty0 + ty) * 256 + tx0 + tx) * 32;
#pragma unroll
    for (int j = 0; j < 4; ++j) {
        short8 o;
#pragma unroll
        for (int e = 0; e < 8; ++e) o[e] = f2bf(vals[j * 8 + e]);
        *(short8*)(yp + j * 8) = o;
    }
    const int lane = tid & 63, wv = tid >> 6;
#pragma unroll
    for (int co = 0; co < 32; ++co) {
        float sm = vals[co], s2 = vals[co] * vals[co];
#pragma unroll
        for (int off = 32; off > 0; off >>= 1) { sm += __shfl_down(sm, off); s2 += __shfl_down(s2, off); }
        if (lane == 0) { s_red[wv][co][0] = sm; s_red[wv][co][1] = s2; }
    }
    __syncthreads();
    if (tid < 32) {
        float S = 0.f, S2 = 0.f;
#pragma unroll
        for (int w = 0; w < 4; ++w) { S += s_red[w][tid][0]; S2 += s_red[w][tid][1]; }
        float* sp = (float*)&stats[(size_t)b * 32 + tid];
        atomicAdd(sp, S); atomicAdd(sp + 1, S2);
    }
}

// ---------------- 2x2 maxpool + fused norm/relu + normalized skip writeback -
// Reads raw conv output; writes pooled+normalized to `out` AND writes the
// normalized skip back in place (skip consumed later by the up-path conv).
__global__ void maxpool_cl(short* __restrict__ in,
                           const float2* __restrict__ st, float invHW,
                           short* __restrict__ out,
                           int c8s, int ws, int hs, int total8)
{
    const int C = 8 << c8s;
    for (int idx = blockIdx.x * 256 + threadIdx.x; idx < total8; idx += gridDim.x * 256) {
        int c8 = idx & ((1 << c8s) - 1);
        int p = idx >> c8s;
        int x = p & ((1 << ws) - 1);
        int yy = (p >> ws) & ((1 << hs) - 1);
        int b = p >> (ws + hs);
        short* ip = in + (((size_t)b * (2 << hs) + 2 * yy) * (2 << ws) + 2 * x) * C + c8 * 8;
        size_t rs = (size_t)(2 << ws) * C;
        short8 v0 = *(const short8*)ip, v1 = *(const short8*)(ip + C);
        short8 v2 = *(const short8*)(ip + rs), v3 = *(const short8*)(ip + rs + C);
        short8 o, w0, w1, w2, w3;
#pragma unroll
        for (int e = 0; e < 8; ++e) {
            float2 sv = st[(size_t)b * C + c8 * 8 + e];
            float mu = sv.x * invHW;
            float rsig = rsqrtf(sv.y * invHW - mu * mu + EPS_IN);
            float n0 = fmaxf(0.f, (bf2f(v0[e]) - mu) * rsig);
            float n1 = fmaxf(0.f, (bf2f(v1[e]) - mu) * rsig);
            float n2 = fmaxf(0.f, (bf2f(v2[e]) - mu) * rsig);
            float n3 = fmaxf(0.f, (bf2f(v3[e]) - mu) * rsig);
            w0[e] = f2bf(n0); w1[e] = f2bf(n1); w2[e] = f2bf(n2); w3[e] = f2bf(n3);
            o[e] = f2bf(fmaxf(fmaxf(n0, n1), fmaxf(n2, n3)));
        }
        *(short8*)ip = w0;
        *(short8*)(ip + C) = w1;
        *(short8*)(ip + rs) = w2;
        *(short8*)(ip + rs + C) = w3;
        *(short8*)(out + (size_t)idx * 8) = o;
    }
}

// ---------------- bilinear 2x upsample + fused norm/relu (pre-lerp) ---------
__global__ void upsample_cl(const short* __restrict__ in,
                            const float2* __restrict__ st, float invHW,
                            short* __restrict__ out,
                            int c8s, int wsi, int hsi, int total8)
{
    const int C = 8 << c8s;
    const int Win = 1 << wsi, Hin = 1 << hsi;
    for (int idx = blockIdx.x * 256 + threadIdx.x; idx < total8; idx += gridDim.x * 256) {
        int c8 = idx & ((1 << c8s) - 1);
        int p = idx >> c8s;
        int x = p & (2 * Win - 1);
        int yy = (p >> (wsi + 1)) & (2 * Hin - 1);
        int b = p >> (wsi + 1 + hsi + 1);
        int xk = x >> 1, yk = yy >> 1;
        int xa, xb; float wxa;
        if (x & 1) { xa = xk; xb = (xk + 1 < Win) ? xk + 1 : Win - 1; wxa = 0.75f; }
        else       { xa = (xk > 0) ? xk - 1 : 0; xb = xk; wxa = 0.25f; }
        int ya, yb; float wya;
        if (yy & 1) { ya = yk; yb = (yk + 1 < Hin) ? yk + 1 : Hin - 1; wya = 0.75f; }
        else        { ya = (yk > 0) ? yk - 1 : 0; yb = yk; wya = 0.25f; }
        const short* ib = in + (size_t)b * Hin * Win * C + c8 * 8;
        short8 vaa = *(const short8*)(ib + ((size_t)ya * Win + xa) * C);
        short8 vab = *(const short8*)(ib + ((size_t)ya * Win + xb) * C);
        short8 vba = *(const short8*)(ib + ((size_t)yb * Win + xa) * C);
        short8 vbb = *(const short8*)(ib + ((size_t)yb * Win + xb) * C);
        short8 o;
#pragma unroll
        for (int e = 0; e < 8; ++e) {
            float2 sv = st[(size_t)b * C + c8 * 8 + e];
            float mu = sv.x * invHW;
            float rsig = rsqrtf(sv.y * invHW - mu * mu + EPS_IN);
            float aa = fmaxf(0.f, (bf2f(vaa[e]) - mu) * rsig);
            float ab = fmaxf(0.f, (bf2f(vab[e]) - mu) * rsig);
            float ba = fmaxf(0.f, (bf2f(vba[e]) - mu) * rsig);
            float bb = fmaxf(0.f, (bf2f(vbb[e]) - mu) * rsig);
            float r0 = wxa * aa + (1.f - wxa) * ab;
            float r1 = wxa * ba + (1.f - wxa) * bb;
            o[e] = f2bf(wya * r0 + (1.f - wya) * r1);
        }
        *(short8*)(out + (size_t)idx * 8) = o;
    }
}

// ---------------- compose the three 1x1 convs into one 32->1 map ------------
__global__ void eff1x1(const float* __restrict__ w1, const float* __restrict__ b1,
                       const float* __restrict__ w2, const float* __restrict__ b2,
                       const float* __restrict__ w3, const float* __restrict__ b3,
                       float* __restrict__ eff)
{
    int t = threadIdx.x;
    if (t < 32) {
        float s = 0.f;
        for (int k = 0; k < 16; ++k) s += w2[k] * w1[k * 32 + t];
        eff[t] = w3[0] * s;
    }
    if (t == 32) {
        float s = 0.f;
        for (int k = 0; k < 16; ++k) s += w2[k] * b1[k];
        eff[32] = w3[0] * (s + b2[0]) + b3[0];
    }
}

// ---------------- final: norm/relu(u3) -> 32->1 conv + residual -------------
__global__ __launch_bounds__(256) void final_pred_cl(
    const short* __restrict__ act, const float2* __restrict__ st, float invHW,
    const float* __restrict__ x0, const float* __restrict__ eff,
    float* __restrict__ pred)
{
    __shared__ float2 s_st[32];
    int idx = blockIdx.x * 256 + threadIdx.x;  // exactly B*65536 threads
    int b = idx >> 16;
    if (threadIdx.x < 32) {
        float2 v = st[(size_t)b * 32 + threadIdx.x];
        float mu = v.x * invHW;
        s_st[threadIdx.x] = make_float2(mu, rsqrtf(v.y * invHW - mu * mu + EPS_IN));
    }
    __syncthreads();
    const short8* a = (const short8*)(act + (size_t)idx * 32);
    float s = eff[32] + x0[idx];
#pragma unroll
    for (int j = 0; j < 4; ++j) {
        short8 v = a[j];
#pragma unroll
        for (int e = 0; e < 8; ++e) {
            float2 sv = s_st[j * 8 + e];
            float f = fmaxf(0.f, (bf2f(v[e]) - sv.x) * sv.y);
            s += eff[j * 8 + e] * f;
        }
    }
    pred[idx] = s;
}

// ---------------- 256-point radix-2 FFT in LDS (one wave) -------------------
__device__ __forceinline__ void fft256(float2* s, int tid, float sign)
{
    __syncthreads();
#pragma unroll
    for (int t = 0; t < 4; ++t) {
        int i = tid + t * 64;
        int r = __brev(i) >> 24;
        if (r > i) { float2 tmp = s[i]; s[i] = s[r]; s[r] = tmp; }
    }
    __syncthreads();
    for (int st = 1; st <= 8; ++st) {
        int m = 1 << st, half = m >> 1;
#pragma unroll
        for (int t = 0; t < 2; ++t) {
            int k = tid + t * 64;
            int g = k >> (st - 1), j = k & (half - 1);
            int i0 = (g << st) + j, i1 = i0 + half;
            float ang = sign * 6.283185307179586f * (float)j / (float)m;
            float sn, cs;
            __sincosf(ang, &sn, &cs);
            float2 a = s[i0], b = s[i1];
            float2 tt = make_float2(b.x * cs - b.y * sn, b.x * sn + b.y * cs);
            s[i0] = make_float2(a.x + tt.x, a.y + tt.y);
            s[i1] = make_float2(a.x - tt.x, a.y - tt.y);
        }
        __syncthreads();
    }
}

__global__ __launch_bounds__(64) void fft_rows_fwd(const float* __restrict__ pred,
                                                   float2* __restrict__ out)
{
    __shared__ float2 s[256];
    int row = blockIdx.x, tid = threadIdx.x;
    const float* p = pred + (size_t)row * 256;
    for (int i = tid; i < 256; i += 64) s[i] = make_float2(p[i], 0.f);
    fft256(s, tid, -1.f);
    float2* o = out + (size_t)row * 256;
    for (int i = tid; i < 256; i += 64) o[i] = s[i];
}

__global__ __launch_bounds__(64) void fft_cols_combine(float2* __restrict__ data,
                                                       const float* __restrict__ ksp,
                                                       const float* __restrict__ mask)
{
    __shared__ float2 s[256];
    int col = blockIdx.x & 255, b = blockIdx.x >> 8;
    int tid = threadIdx.x;
    float2* base = data + (size_t)b * 65536 + col;
    for (int i = tid; i < 256; i += 64) s[i] = base[(size_t)i * 256];
    fft256(s, tid, -1.f);
    for (int i = tid; i < 256; i += 64) {
        size_t mi = ((size_t)b * 256 + i) * 256 + col;
        float m = mask[mi];
        float2 kp = s[i];
        float kr = ksp[mi * 2], ki = ksp[mi * 2 + 1];
        s[i] = make_float2(m * kr + (1.f - m) * kp.x * (1.f / 256.f),
                           m * ki + (1.f - m) * kp.y * (1.f / 256.f));
    }
    fft256(s, tid, 1.f);
    for (int i = tid; i < 256; i += 64) base[(size_t)i * 256] = s[i];
}

__global__ __launch_bounds__(64) void fft_rows_inv(const float2* __restrict__ data,
                                                   float* __restrict__ out)
{
    __shared__ float2 s[256];
    int row = blockIdx.x, tid = threadIdx.x;
    const float2* p = data + (size_t)row * 256;
    for (int i = tid; i < 256; i += 64) s[i] = p[i];
    fft256(s, tid, 1.f);
    float* o = out + (size_t)row * 256;
    for (int i = tid; i < 256; i += 64) o[i] = s[i].x * (1.f / 256.f);
}

// ---------------------------------------------------------------------------
extern "C" void kernel_launch(void* const* d_in, const int* in_sizes, int n_in,
                              void* d_out, int out_size, void* d_ws, size_t ws_size,
                              hipStream_t stream)
{
    (void)in_sizes; (void)n_in; (void)out_size; (void)ws_size;

    const float* x0 = (const float*)d_in[0];
    const float* ksp = (const float*)d_in[1];
    const float* mask = (const float*)d_in[2];
    const float* mod_d[4] = {(const float*)d_in[3], (const float*)d_in[6],
                             (const float*)d_in[9], (const float*)d_in[12]};
    const float* W_d[4] = {(const float*)d_in[4], (const float*)d_in[7],
                           (const float*)d_in[10], (const float*)d_in[13]};
    const float* mod_lat = (const float*)d_in[15];
    const float* W_lat = (const float*)d_in[16];
    const float* mod_u[4] = {(const float*)d_in[18], (const float*)d_in[21],
                             (const float*)d_in[24], (const float*)d_in[27]};
    const float* W_u[4] = {(const float*)d_in[19], (const float*)d_in[22],
                           (const float*)d_in[25], (const float*)d_in[28]};
    const float* w_c1 = (const float*)d_in[30];
    const float* b_c1 = (const float*)d_in[31];
    const float* w_c2 = (const float*)d_in[32];
    const float* b_c2 = (const float*)d_in[33];
    const float* w_c3 = (const float*)d_in[34];
    const float* b_c3 = (const float*)d_in[35];

    // ---- workspace layout (CL bf16 activations), ~146 MB
    short* sA  = (short*)d_ws;          // 16,777,216
    short* sB  = sA + 16777216;         // 16,777,216
    short* sk0 = sB + 16777216;         // 16,777,216 (8,256,256,32)
    short* sk1 = sk0 + 16777216;        //  8,388,608 (8,128,128,64)
    short* sk2 = sk1 + 8388608;         //  4,194,304 (8,64,64,128)
    short* sk3 = sk2 + 4194304;         //  2,097,152 (8,32,32,256)
    short* wm  = sk3 + 2097152;         //  4,718,592 (JIT wm scratch)
    float* pred = (float*)(wm + 4718592);      // 524,288
    float2* cplx = (float2*)(pred + 524288);   // 524,288 float2
    float2* stA = cplx + 524288;               // 7,936 float2 stat accumulators
    float* eff = (float*)(stA + 7936);         // 64

    // per-layer stat slices
    float2* st_d0 = stA + 0;
    float2* st_d1 = stA + 256;
    float2* st_d2 = stA + 768;
    float2* st_d3 = stA + 1792;
    float2* st_lat = stA + 3840;
    float2* st_u0 = stA + 5888;
    float2* st_u1 = stA + 6912;
    float2* st_u2 = stA + 7424;
    float2* st_u3 = stA + 7680;

    const float i64k = 1.f / 65536.f, i16k = 1.f / 16384.f, i4k = 1.f / 4096.f,
                i1k = 1.f / 1024.f, i256 = 1.f / 256.f;

    dim3 blk(256);

    zero_f<<<62, blk, 0, stream>>>((float*)stA, 15872);
    eff1x1<<<1, 64, 0, stream>>>(w_c1, b_c1, w_c2, b_c2, w_c3, b_c3, eff);

    // ---- down 0: 1 -> 32 @256 (raw out + stats); pool norms + writes back sk0
    conv_d0_cl<<<dim3(256, 8), blk, 0, stream>>>(x0, W_d[0], mod_d[0], sk0, st_d0);
    maxpool_cl<<<2048, blk, 0, stream>>>(sk0, st_d0, i64k, sA, 2, 7, 7, 524288);

    // ---- down 1: 32 -> 64 @128
    make_wm<<<(8 * 64 * 32 + 255) / 256, blk, 0, stream>>>(W_d[1], mod_d[1], wm, 64, 32);
    conv3x3_cl<4, 4><<<dim3(64, 1, 8), blk, 0, stream>>>(sA, 32, sA, wm, sk1, st_d1, 32, 64, 128, 128);
    maxpool_cl<<<1024, blk, 0, stream>>>(sk1, st_d1, i16k, sA, 3, 6, 6, 262144);

    // ---- down 2: 64 -> 128 @64
    make_wm<<<(8 * 128 * 64 + 255) / 256, blk, 0, stream>>>(W_d[2], mod_d[2], wm, 128, 64);
    conv3x3_cl<2, 4><<<dim3(32, 2, 8), blk, 0, stream>>>(sA, 64, sA, wm, sk2, st_d2, 64, 128, 64, 64);
    maxpool_cl<<<512, blk, 0, stream>>>(sk2, st_d2, i4k, sA, 4, 5, 5, 131072);

    // ---- down 3: 128 -> 256 @32
    make_wm<<<(8 * 256 * 128 + 255) / 256, blk, 0, stream>>>(W_d[3], mod_d[3], wm, 256, 128);
    conv3x3_cl<2, 2><<<dim3(8, 8, 8), blk, 0, stream>>>(sA, 128, sA, wm, sk3, st_d3, 128, 256, 32, 32);
    maxpool_cl<<<256, blk, 0, stream>>>(sk3, st_d3, i1k, sA, 5, 4, 4, 65536);

    // ---- latent: 256 -> 256 @16 (raw out; upsample normalizes)
    make_wm<<<(8 * 256 * 256 + 255) / 256, blk, 0, stream>>>(W_lat, mod_lat, wm, 256, 256);
    conv3x3_cl<2, 1><<<dim3(2, 16, 8), blk, 0, stream>>>(sA, 256, sA, wm, sB, st_lat, 256, 256, 16, 16);

    // ---- up 0: up(norm(lat)@16->32) ++ sk3(normalized) -> 128 @32
    upsample_cl<<<1024, blk, 0, stream>>>(sB, st_lat, i256, sA, 5, 4, 4, 262144);
    make_wm<<<(8 * 128 * 512 + 255) / 256, blk, 0, stream>>>(W_u[0], mod_u[0], wm, 128, 512);
    conv3x3_cl<2, 1><<<dim3(8, 8, 8), blk, 0, stream>>>(sA, 256, sk3, wm, sB, st_u0, 512, 128, 32, 32);

    // ---- up 1: up(norm(u0)@32->64) ++ sk2(normalized) -> 64 @64
    upsample_cl<<<2048, blk, 0, stream>>>(sB, st_u0, i1k, sA, 4, 5, 5, 524288);
    make_wm<<<(8 * 64 * 256 + 255) / 256, blk, 0, stream>>>(W_u[1], mod_u[1], wm, 64, 256);
    conv3x3_cl<2, 2><<<dim3(32, 2, 8), blk, 0, stream>>>(sA, 128, sk2, wm, sB, st_u1, 256, 64, 64, 64);

    // ---- up 2: up(norm(u1)@64->128) ++ sk1(normalized) -> 32 @128
    upsample_cl<<<4096, blk, 0, stream>>>(sB, st_u1, i4k, sA, 3, 6, 6, 1048576);
    make_wm<<<(8 * 32 * 128 + 255) / 256, blk, 0, stream>>>(W_u[2], mod_u[2], wm, 32, 128);
    conv3x3_cl<4, 2><<<dim3(64, 1, 8), blk, 0, stream>>>(sA, 64, sk1, wm, sB, st_u2, 128, 32, 128, 128);

    // ---- up 3: up(norm(u2)@128->256) ++ sk0(normalized) -> 32 @256
    upsample_cl<<<8192, blk, 0, stream>>>(sB, st_u2, i16k, sA, 2, 7, 7, 2097152);
    make_wm<<<(8 * 32 * 64 + 255) / 256, blk, 0, stream>>>(W_u[3], mod_u[3], wm, 32, 64);
    conv3x3_cl<4, 2><<<dim3(256, 1, 8), blk, 0, stream>>>(sA, 32, sk0, wm, sB, st_u3, 64, 32, 256, 256);

    // ---- fused norm(u3) + 1x1 chain + residual
    final_pred_cl<<<2048, blk, 0, stream>>>(sB, st_u3, i64k, x0, eff, pred);

    // ---- FFT data consistency
    fft_rows_fwd<<<2048, 64, 0, stream>>>(pred, cplx);
    fft_cols_combine<<<2048, 64, 0, stream>>>(cplx, ksp, mask);
    fft_rows_inv<<<2048, 64, 0, stream>>>(cplx, (float*)d_out);
}

// Round 8
// 501.780 us; speedup vs baseline: 1.1551x; 1.0329x over previous
//
#include <hip/hip_runtime.h>

// ---------------------------------------------------------------------------
// UnetMACReconNet: modulated-conv UNet + IN/ReLU + FFT data consistency
// Round 8: upsample+norm fused into up-conv staging (no upsample kernels),
//          single make_wm_all launch, final_pred fused into row-FFT,
//          XCD batch-pinned 1-D conv grids. Conv MFMA core = R4/R7 proven.
// ---------------------------------------------------------------------------

#define EPS_IN 1e-5f

typedef __attribute__((ext_vector_type(8))) short short8;
typedef __attribute__((ext_vector_type(4))) short short4_t;
typedef __attribute__((ext_vector_type(4))) float f32x4;

__device__ __forceinline__ short f2bf(float f) {
    unsigned u = __float_as_uint(f);
    unsigned r = (u + 0x7fffu + ((u >> 16) & 1u)) >> 16;
    return (short)r;
}
__device__ __forceinline__ float bf2f(short s) {
    return __uint_as_float(((unsigned)(unsigned short)s) << 16);
}

// ---------------- zero the stat accumulators --------------------------------
__global__ void zero_f(float* __restrict__ p, int n)
{
    int i = blockIdx.x * 256 + threadIdx.x;
    if (i < n) p[i] = 0.f;
}

// ---------------- all-layer modded bf16 weights in one launch ---------------
struct WmJobs {
    const float* W[8];
    const float* mod[8];
    short* wm[8];
    int Co[8];
    int Ci[8];
    int cum[9];   // cumulative 8*Co*Ci
};

__global__ void make_wm_all(WmJobs j)
{
    int idx = blockIdx.x * 256 + threadIdx.x;
    if (idx >= j.cum[8]) return;
    int l = 0;
    while (idx >= j.cum[l + 1]) ++l;
    int local = idx - j.cum[l];
    const int Ci = j.Ci[l], Co = j.Co[l];
    int ci = local % Ci;
    int rem = local / Ci;
    int co = rem % Co;
    int b = rem / Co;
    const float* wp = j.W[l] + (size_t)(co * Ci + ci) * 9;
    const float* mp = j.mod[l] + ((size_t)((size_t)b * Co + co) * Ci + ci) * 9;
    short* wm = j.wm[l];
#pragma unroll
    for (int k = 0; k < 9; ++k)
        wm[(((size_t)(b * 9 + k) * Co + co) * Ci + ci)] = f2bf(wp[k] * mp[k]);
}

// ---------------- MFMA conv3x3, CL, fused IN-stats; optional fused upsample -
// UP=false: x1 (and x2) are full-res normalized inputs (R7 behavior).
// UP=true : x1 = RAW low-res source (H/2 x W/2, Ci1 ch) normalized+bilinear-
//           upsampled during staging via st1*invHW1; x2 = normalized skip.
// 1-D grid, XCD-pinned: blockIdx.x & 7 == batch.
template <int VR, int NCOG, bool UP>
__global__ __launch_bounds__(256) void conv3x3_cl(
    const short* __restrict__ x1, int Ci1,
    const short* __restrict__ x2,
    const float2* __restrict__ st1, float invHW1,
    const short* __restrict__ wm,   // [b][9][Co][Ci] bf16
    short* __restrict__ y,
    float2* __restrict__ stats,
    int Ci, int Co, int H, int W)
{
    constexpr int TH = 4 * VR, SH = TH + 2, SW = 18;
    constexpr int STN = UP ? 256 : 1;
    __shared__ short s_x[SH][SW][32];
    __shared__ float s_red[4][4][NCOG][4][2];
    __shared__ float2 s_st1[STN];

    const int tid = threadIdx.x;
    const int lane = tid & 63, wv = tid >> 6;
    const int m = lane & 15, g = lane >> 4;

    const int b = blockIdx.x & 7;
    int r = blockIdx.x >> 3;
    const int nCoB = Co / (16 * NCOG);
    const int coblk = r % nCoB;
    const int tileId = r / nCoB;
    const int tilesx = W >> 4;
    const int tx0 = (tileId % tilesx) * 16;
    const int ty0 = (tileId / tilesx) * TH;
    const int co0 = coblk * (16 * NCOG);
    const int Ci2 = Ci - Ci1;
    const int Hs = H >> 1, Ws = W >> 1;

    if (UP) {
        for (int i = tid; i < Ci1; i += 256) {
            float2 v = st1[(size_t)b * Ci1 + i];
            float mu = v.x * invHW1;
            float var = v.y * invHW1 - mu * mu;
            s_st1[i] = make_float2(mu, rsqrtf(var + EPS_IN));
        }
    }

    f32x4 acc[NCOG][VR];
#pragma unroll
    for (int cg = 0; cg < NCOG; ++cg)
#pragma unroll
        for (int rr = 0; rr < VR; ++rr) acc[cg][rr] = (f32x4)0.f;

    const short* wmb = wm + (size_t)b * 9 * Co * Ci;
    const short* x1b = x1 + (size_t)b * (UP ? (size_t)Hs * Ws : (size_t)H * W) * Ci1;
    const short* x2b = x2 + (size_t)b * H * W * Ci2;

    for (int ci0 = 0; ci0 < Ci; ci0 += 32) {
        __syncthreads();   // prev MFMA done; s_st1 ready on first iter
        if (UP && ci0 < Ci1) {
            // ---- fused norm + bilinear upsample staging from raw low-res x1
            const int cb = ci0;
            for (int idx = tid; idx < SH * SW * 4; idx += 256) {
                int gg = idx & 3, pos = idx >> 2;
                int yy = pos / SW, xx = pos - yy * SW;
                int gy = ty0 + yy - 1, gx = tx0 + xx - 1;
                short8 v = (short8)0;
                if (gy >= 0 && gy < H && gx >= 0 && gx < W) {
                    int xk = gx >> 1, yk = gy >> 1;
                    int xo = gx & 1, yo = gy & 1;
                    int xa = xo ? xk : (xk > 0 ? xk - 1 : 0);
                    int xb = xo ? (xk + 1 < Ws ? xk + 1 : Ws - 1) : xk;
                    float wxa = xo ? 0.75f : 0.25f;
                    int ya = yo ? yk : (yk > 0 ? yk - 1 : 0);
                    int yb = yo ? (yk + 1 < Hs ? yk + 1 : Hs - 1) : yk;
                    float wya = yo ? 0.75f : 0.25f;
                    const short* ib = x1b + cb + gg * 8;
                    short8 vaa = *(const short8*)(ib + ((size_t)ya * Ws + xa) * Ci1);
                    short8 vab = *(const short8*)(ib + ((size_t)ya * Ws + xb) * Ci1);
                    short8 vba = *(const short8*)(ib + ((size_t)yb * Ws + xa) * Ci1);
                    short8 vbb = *(const short8*)(ib + ((size_t)yb * Ws + xb) * Ci1);
#pragma unroll
                    for (int e = 0; e < 8; ++e) {
                        float2 sv = s_st1[cb + gg * 8 + e];
                        float aa = fmaxf(0.f, (bf2f(vaa[e]) - sv.x) * sv.y);
                        float ab = fmaxf(0.f, (bf2f(vab[e]) - sv.x) * sv.y);
                        float ba = fmaxf(0.f, (bf2f(vba[e]) - sv.x) * sv.y);
                        float bb = fmaxf(0.f, (bf2f(vbb[e]) - sv.x) * sv.y);
                        float r0 = wxa * aa + (1.f - wxa) * ab;
                        float r1 = wxa * ba + (1.f - wxa) * bb;
                        v[e] = f2bf(wya * r0 + (1.f - wya) * r1);
                    }
                }
                *(short8*)&s_x[yy][xx][(gg ^ (xx & 3)) * 8] = v;
            }
        } else {
            const short* src; int C, cb;
            if (ci0 < Ci1) { src = x1b; C = Ci1; cb = ci0; }
            else           { src = x2b; C = Ci2; cb = ci0 - Ci1; }
            for (int idx = tid; idx < SH * SW * 4; idx += 256) {
                int gg = idx & 3, pos = idx >> 2;
                int yy = pos / SW, xx = pos - yy * SW;
                int gy = ty0 + yy - 1, gx = tx0 + xx - 1;
                short8 v = (short8)0;
                if (gy >= 0 && gy < H && gx >= 0 && gx < W)
                    v = *(const short8*)(src + ((size_t)gy * W + gx) * C + cb + gg * 8);
                *(short8*)&s_x[yy][xx][(gg ^ (xx & 3)) * 8] = v;
            }
        }
        __syncthreads();
#pragma unroll
        for (int t = 0; t < 9; ++t) {
            const int dy = t / 3, dx = t - 3 * (t / 3);
            const short* wr = wmb + ((size_t)t * Co + co0) * Ci + ci0 + g * 8;
            short8 a[NCOG];
#pragma unroll
            for (int cg = 0; cg < NCOG; ++cg)
                a[cg] = *(const short8*)(wr + (size_t)(cg * 16 + m) * Ci);
            const int xx = m + dx;
            const int sgo = (g ^ (xx & 3)) * 8;
#pragma unroll
            for (int rr = 0; rr < VR; ++rr) {
                short8 bf = *(const short8*)&s_x[wv * VR + rr + dy][xx][sgo];
#pragma unroll
                for (int cg = 0; cg < NCOG; ++cg)
                    acc[cg][rr] = __builtin_amdgcn_mfma_f32_16x16x32_bf16(a[cg], bf, acc[cg][rr], 0, 0, 0);
            }
        }
    }

    // ---- writeout (CL: 4 consecutive co per lane) + fused stats
    const int ox = tx0 + m;
#pragma unroll
    for (int cg = 0; cg < NCOG; ++cg)
#pragma unroll
        for (int rr = 0; rr < VR; ++rr) {
            int oy = ty0 + wv * VR + rr;
            short4_t o;
#pragma unroll
            for (int q = 0; q < 4; ++q) o[q] = f2bf(acc[cg][rr][q]);
            *(short4_t*)(y + (((size_t)b * H + oy) * W + ox) * Co + co0 + cg * 16 + g * 4) = o;
        }

#pragma unroll
    for (int cg = 0; cg < NCOG; ++cg)
#pragma unroll
        for (int q = 0; q < 4; ++q) {
            float s = 0.f, s2 = 0.f;
#pragma unroll
            for (int rr = 0; rr < VR; ++rr) { float v = acc[cg][rr][q]; s += v; s2 += v * v; }
#pragma unroll
            for (int msk = 1; msk < 16; msk <<= 1) { s += __shfl_xor(s, msk); s2 += __shfl_xor(s2, msk); }
            if (m == 0) { s_red[wv][g][cg][q][0] = s; s_red[wv][g][cg][q][1] = s2; }
        }
    __syncthreads();
    for (int i = tid; i < 16 * NCOG; i += 256) {
        int q = i & 3, gg = (i >> 2) & 3, cg = i >> 4;
        float S = 0.f, S2 = 0.f;
#pragma unroll
        for (int w = 0; w < 4; ++w) { S += s_red[w][gg][cg][q][0]; S2 += s_red[w][gg][cg][q][1]; }
        float* sp = (float*)&stats[(size_t)b * Co + co0 + i];
        atomicAdd(sp, S); atomicAdd(sp + 1, S2);
    }
}

// ---------------- d0 conv: Ci=1, Co=32, fp32 NCHW in -> CL bf16 raw out -----
__global__ __launch_bounds__(256) void conv_d0_cl(
    const float* __restrict__ x0, const float* __restrict__ W,
    const float* __restrict__ mod, short* __restrict__ y,
    float2* __restrict__ stats)
{
    __shared__ float s[18][18];
    __shared__ float sw[32][9];
    __shared__ float s_red[4][32][2];
    const int tid = threadIdx.x;
    const int tx = tid & 15, ty = tid >> 4;
    const int tx0 = (blockIdx.x & 15) * 16, ty0 = (blockIdx.x >> 4) * 16;
    const int b = blockIdx.y;
    if (tid < 288) sw[tid / 9][tid % 9] = W[tid] * mod[b * 288 + tid];
    for (int pos = tid; pos < 18 * 18; pos += 256) {
        int yy = pos / 18, xx = pos - yy * 18;
        int gy = ty0 + yy - 1, gx = tx0 + xx - 1;
        bool inb = gy >= 0 && gy < 256 && gx >= 0 && gx < 256;
        s[yy][xx] = inb ? x0[((size_t)b << 16) + gy * 256 + gx] : 0.f;
    }
    __syncthreads();
    float v[3][3];
#pragma unroll
    for (int r = 0; r < 3; ++r)
#pragma unroll
        for (int c = 0; c < 3; ++c) v[r][c] = s[ty + r][tx + c];
    float vals[32];
#pragma unroll
    for (int co = 0; co < 32; ++co) {
        float a = 0.f;
#pragma unroll
        for (int r = 0; r < 3; ++r)
#pragma unroll
            for (int c = 0; c < 3; ++c) a = fmaf(v[r][c], sw[co][r * 3 + c], a);
        vals[co] = a;
    }
    short* yp = y + (((size_t)b * 256 + ty0 + ty) * 256 + tx0 + tx) * 32;
#pragma unroll
    for (int j = 0; j < 4; ++j) {
        short8 o;
#pragma unroll
        for (int e = 0; e < 8; ++e) o[e] = f2bf(vals[j * 8 + e]);
        *(short8*)(yp + j * 8) = o;
    }
    const int lane = tid & 63, wv = tid >> 6;
#pragma unroll
    for (int co = 0; co < 32; ++co) {
        float sm = vals[co], s2 = vals[co] * vals[co];
#pragma unroll
        for (int off = 32; off > 0; off >>= 1) { sm += __shfl_down(sm, off); s2 += __shfl_down(s2, off); }
        if (lane == 0) { s_red[wv][co][0] = sm; s_red[wv][co][1] = s2; }
    }
    __syncthreads();
    if (tid < 32) {
        float S = 0.f, S2 = 0.f;
#pragma unroll
        for (int w = 0; w < 4; ++w) { S += s_red[w][tid][0]; S2 += s_red[w][tid][1]; }
        float* sp = (float*)&stats[(size_t)b * 32 + tid];
        atomicAdd(sp, S); atomicAdd(sp + 1, S2);
    }
}

// ---------------- 2x2 maxpool + fused norm/relu + normalized skip writeback -
__global__ void maxpool_cl(short* __restrict__ in,
                           const float2* __restrict__ st, float invHW,
                           short* __restrict__ out,
                           int c8s, int ws, int hs, int total8)
{
    const int C = 8 << c8s;
    for (int idx = blockIdx.x * 256 + threadIdx.x; idx < total8; idx += gridDim.x * 256) {
        int c8 = idx & ((1 << c8s) - 1);
        int p = idx >> c8s;
        int x = p & ((1 << ws) - 1);
        int yy = (p >> ws) & ((1 << hs) - 1);
        int b = p >> (ws + hs);
        short* ip = in + (((size_t)b * (2 << hs) + 2 * yy) * (2 << ws) + 2 * x) * C + c8 * 8;
        size_t rs = (size_t)(2 << ws) * C;
        short8 v0 = *(const short8*)ip, v1 = *(const short8*)(ip + C);
        short8 v2 = *(const short8*)(ip + rs), v3 = *(const short8*)(ip + rs + C);
        short8 o, w0, w1, w2, w3;
#pragma unroll
        for (int e = 0; e < 8; ++e) {
            float2 sv = st[(size_t)b * C + c8 * 8 + e];
            float mu = sv.x * invHW;
            float rsig = rsqrtf(sv.y * invHW - mu * mu + EPS_IN);
            float n0 = fmaxf(0.f, (bf2f(v0[e]) - mu) * rsig);
            float n1 = fmaxf(0.f, (bf2f(v1[e]) - mu) * rsig);
            float n2 = fmaxf(0.f, (bf2f(v2[e]) - mu) * rsig);
            float n3 = fmaxf(0.f, (bf2f(v3[e]) - mu) * rsig);
            w0[e] = f2bf(n0); w1[e] = f2bf(n1); w2[e] = f2bf(n2); w3[e] = f2bf(n3);
            o[e] = f2bf(fmaxf(fmaxf(n0, n1), fmaxf(n2, n3)));
        }
        *(short8*)ip = w0;
        *(short8*)(ip + C) = w1;
        *(short8*)(ip + rs) = w2;
        *(short8*)(ip + rs + C) = w3;
        *(short8*)(out + (size_t)idx * 8) = o;
    }
}

// ---------------- compose the three 1x1 convs into one 32->1 map ------------
__global__ void eff1x1(const float* __restrict__ w1, const float* __restrict__ b1,
                       const float* __restrict__ w2, const float* __restrict__ b2,
                       const float* __restrict__ w3, const float* __restrict__ b3,
                       float* __restrict__ eff)
{
    int t = threadIdx.x;
    if (t < 32) {
        float s = 0.f;
        for (int k = 0; k < 16; ++k) s += w2[k] * w1[k * 32 + t];
        eff[t] = w3[0] * s;
    }
    if (t == 32) {
        float s = 0.f;
        for (int k = 0; k < 16; ++k) s += w2[k] * b1[k];
        eff[32] = w3[0] * (s + b2[0]) + b3[0];
    }
}

// ---------------- 256-point radix-2 FFT in LDS (one wave) -------------------
__device__ __forceinline__ void fft256(float2* s, int tid, float sign)
{
    __syncthreads();
#pragma unroll
    for (int t = 0; t < 4; ++t) {
        int i = tid + t * 64;
        int r = __brev(i) >> 24;
        if (r > i) { float2 tmp = s[i]; s[i] = s[r]; s[r] = tmp; }
    }
    __syncthreads();
    for (int st = 1; st <= 8; ++st) {
        int m = 1 << st, half = m >> 1;
#pragma unroll
        for (int t = 0; t < 2; ++t) {
            int k = tid + t * 64;
            int g = k >> (st - 1), j = k & (half - 1);
            int i0 = (g << st) + j, i1 = i0 + half;
            float ang = sign * 6.283185307179586f * (float)j / (float)m;
            float sn, cs;
            __sincosf(ang, &sn, &cs);
            float2 a = s[i0], b = s[i1];
            float2 tt = make_float2(b.x * cs - b.y * sn, b.x * sn + b.y * cs);
            s[i0] = make_float2(a.x + tt.x, a.y + tt.y);
            s[i1] = make_float2(a.x - tt.x, a.y - tt.y);
        }
        __syncthreads();
    }
}

// ---------------- fused: norm(u3) + 1x1 chain + residual + row FFT ----------
__global__ __launch_bounds__(64) void final_fft_rows(
    const short* __restrict__ act, const float2* __restrict__ st, float invHW,
    const float* __restrict__ x0, const float* __restrict__ eff,
    float2* __restrict__ cplx)
{
    __shared__ float2 s[256];
    __shared__ float2 sst[32];
    __shared__ float seff[33];
    const int row = blockIdx.x, tid = threadIdx.x;
    const int b = row >> 8, yy = row & 255;
    if (tid < 32) {
        float2 v = st[(size_t)b * 32 + tid];
        float mu = v.x * invHW;
        sst[tid] = make_float2(mu, rsqrtf(v.y * invHW - mu * mu + EPS_IN));
    }
    if (tid < 33) seff[tid] = eff[tid];
    __syncthreads();
#pragma unroll
    for (int k = 0; k < 4; ++k) {
        int x = k * 64 + tid;
        const short8* a = (const short8*)(act + (((size_t)b * 256 + yy) * 256 + x) * 32);
        float sacc = seff[32] + x0[((size_t)b << 16) + (yy << 8) + x];
#pragma unroll
        for (int j = 0; j < 4; ++j) {
            short8 v = a[j];
#pragma unroll
            for (int e = 0; e < 8; ++e) {
                float2 sv = sst[j * 8 + e];
                sacc += seff[j * 8 + e] * fmaxf(0.f, (bf2f(v[e]) - sv.x) * sv.y);
            }
        }
        s[x] = make_float2(sacc, 0.f);
    }
    fft256(s, tid, -1.f);
    float2* o = cplx + (size_t)row * 256;
    for (int i = tid; i < 256; i += 64) o[i] = s[i];
}

__global__ __launch_bounds__(64) void fft_cols_combine(float2* __restrict__ data,
                                                       const float* __restrict__ ksp,
                                                       const float* __restrict__ mask)
{
    __shared__ float2 s[256];
    int col = blockIdx.x & 255, b = blockIdx.x >> 8;
    int tid = threadIdx.x;
    float2* base = data + (size_t)b * 65536 + col;
    for (int i = tid; i < 256; i += 64) s[i] = base[(size_t)i * 256];
    fft256(s, tid, -1.f);
    for (int i = tid; i < 256; i += 64) {
        size_t mi = ((size_t)b * 256 + i) * 256 + col;
        float m = mask[mi];
        float2 kp = s[i];
        float kr = ksp[mi * 2], ki = ksp[mi * 2 + 1];
        s[i] = make_float2(m * kr + (1.f - m) * kp.x * (1.f / 256.f),
                           m * ki + (1.f - m) * kp.y * (1.f / 256.f));
    }
    fft256(s, tid, 1.f);
    for (int i = tid; i < 256; i += 64) base[(size_t)i * 256] = s[i];
}

__global__ __launch_bounds__(64) void fft_rows_inv(const float2* __restrict__ data,
                                                   float* __restrict__ out)
{
    __shared__ float2 s[256];
    int row = blockIdx.x, tid = threadIdx.x;
    const float2* p = data + (size_t)row * 256;
    for (int i = tid; i < 256; i += 64) s[i] = p[i];
    fft256(s, tid, 1.f);
    float* o = out + (size_t)row * 256;
    for (int i = tid; i < 256; i += 64) o[i] = s[i].x * (1.f / 256.f);
}

// ---------------------------------------------------------------------------
extern "C" void kernel_launch(void* const* d_in, const int* in_sizes, int n_in,
                              void* d_out, int out_size, void* d_ws, size_t ws_size,
                              hipStream_t stream)
{
    (void)in_sizes; (void)n_in; (void)out_size; (void)ws_size;

    const float* x0 = (const float*)d_in[0];
    const float* ksp = (const float*)d_in[1];
    const float* mask = (const float*)d_in[2];
    const float* mod_d[4] = {(const float*)d_in[3], (const float*)d_in[6],
                             (const float*)d_in[9], (const float*)d_in[12]};
    const float* W_d[4] = {(const float*)d_in[4], (const float*)d_in[7],
                           (const float*)d_in[10], (const float*)d_in[13]};
    const float* mod_lat = (const float*)d_in[15];
    const float* W_lat = (const float*)d_in[16];
    const float* mod_u[4] = {(const float*)d_in[18], (const float*)d_in[21],
                             (const float*)d_in[24], (const float*)d_in[27]};
    const float* W_u[4] = {(const float*)d_in[19], (const float*)d_in[22],
                           (const float*)d_in[25], (const float*)d_in[28]};
    const float* w_c1 = (const float*)d_in[30];
    const float* b_c1 = (const float*)d_in[31];
    const float* w_c2 = (const float*)d_in[32];
    const float* b_c2 = (const float*)d_in[33];
    const float* w_c3 = (const float*)d_in[34];
    const float* b_c3 = (const float*)d_in[35];

    // ---- workspace layout (CL bf16 activations), ~165 MB
    short* sA  = (short*)d_ws;          // 16,777,216
    short* sB  = sA + 16777216;         // 16,777,216
    short* sk0 = sB + 16777216;         // 16,777,216 (8,256,256,32)
    short* sk1 = sk0 + 16777216;        //  8,388,608 (8,128,128,64)
    short* sk2 = sk1 + 8388608;         //  4,194,304 (8,64,64,128)
    short* sk3 = sk2 + 4194304;         //  2,097,152 (8,32,32,256)
    short* wm_d1 = sk3 + 2097152;       //    147,456
    short* wm_d2 = wm_d1 + 147456;      //    589,824
    short* wm_d3 = wm_d2 + 589824;      //  2,359,296
    short* wm_lat = wm_d3 + 2359296;    //  4,718,592
    short* wm_u0 = wm_lat + 4718592;    //  4,718,592
    short* wm_u1 = wm_u0 + 4718592;     //  1,179,648
    short* wm_u2 = wm_u1 + 1179648;     //    294,912
    short* wm_u3 = wm_u2 + 294912;      //    147,456
    float2* cplx = (float2*)(wm_u3 + 147456);  // 524,288 float2
    float2* stA = cplx + 524288;               // 7,936 float2 stat accumulators
    float* eff = (float*)(stA + 7936);         // 64

    // per-layer stat slices
    float2* st_d0 = stA + 0;
    float2* st_d1 = stA + 256;
    float2* st_d2 = stA + 768;
    float2* st_d3 = stA + 1792;
    float2* st_lat = stA + 3840;
    float2* st_u0 = stA + 5888;
    float2* st_u1 = stA + 6912;
    float2* st_u2 = stA + 7424;
    float2* st_u3 = stA + 7680;

    const float i64k = 1.f / 65536.f, i16k = 1.f / 16384.f, i4k = 1.f / 4096.f,
                i1k = 1.f / 1024.f, i256 = 1.f / 256.f;

    dim3 blk(256);

    zero_f<<<62, blk, 0, stream>>>((float*)stA, 15872);
    eff1x1<<<1, 64, 0, stream>>>(w_c1, b_c1, w_c2, b_c2, w_c3, b_c3, eff);

    // ---- all modded weights, one launch
    WmJobs jobs;
    const float* Wl[8]  = {W_d[1], W_d[2], W_d[3], W_lat, W_u[0], W_u[1], W_u[2], W_u[3]};
    const float* Ml[8]  = {mod_d[1], mod_d[2], mod_d[3], mod_lat, mod_u[0], mod_u[1], mod_u[2], mod_u[3]};
    short* WMl[8] = {wm_d1, wm_d2, wm_d3, wm_lat, wm_u0, wm_u1, wm_u2, wm_u3};
    int Col[8] = {64, 128, 256, 256, 128, 64, 32, 32};
    int Cil[8] = {32, 64, 128, 256, 512, 256, 128, 64};
    jobs.cum[0] = 0;
    for (int l = 0; l < 8; ++l) {
        jobs.W[l] = Wl[l]; jobs.mod[l] = Ml[l]; jobs.wm[l] = WMl[l];
        jobs.Co[l] = Col[l]; jobs.Ci[l] = Cil[l];
        jobs.cum[l + 1] = jobs.cum[l] + 8 * Col[l] * Cil[l];
    }
    make_wm_all<<<(jobs.cum[8] + 255) / 256, blk, 0, stream>>>(jobs);

    // ---- down path
    conv_d0_cl<<<dim3(256, 8), blk, 0, stream>>>(x0, W_d[0], mod_d[0], sk0, st_d0);
    maxpool_cl<<<2048, blk, 0, stream>>>(sk0, st_d0, i64k, sA, 2, 7, 7, 524288);

    conv3x3_cl<4, 4, false><<<512, blk, 0, stream>>>(sA, 32, sA, stA, 0.f, wm_d1, sk1, st_d1, 32, 64, 128, 128);
    maxpool_cl<<<1024, blk, 0, stream>>>(sk1, st_d1, i16k, sA, 3, 6, 6, 262144);

    conv3x3_cl<2, 4, false><<<512, blk, 0, stream>>>(sA, 64, sA, stA, 0.f, wm_d2, sk2, st_d2, 64, 128, 64, 64);
    maxpool_cl<<<512, blk, 0, stream>>>(sk2, st_d2, i4k, sA, 4, 5, 5, 131072);

    conv3x3_cl<2, 2, false><<<512, blk, 0, stream>>>(sA, 128, sA, stA, 0.f, wm_d3, sk3, st_d3, 128, 256, 32, 32);
    maxpool_cl<<<256, blk, 0, stream>>>(sk3, st_d3, i1k, sA, 5, 4, 4, 65536);

    conv3x3_cl<2, 1, false><<<256, blk, 0, stream>>>(sA, 256, sA, stA, 0.f, wm_lat, sB, st_lat, 256, 256, 16, 16);

    // ---- up path: bilinear+norm fused into conv staging (x1 = raw low-res)
    conv3x3_cl<2, 1, true><<<512, blk, 0, stream>>>(sB, 256, sk3, st_lat, i256, wm_u0, sA, st_u0, 512, 128, 32, 32);
    conv3x3_cl<2, 2, true><<<512, blk, 0, stream>>>(sA, 128, sk2, st_u0, i1k, wm_u1, sB, st_u1, 256, 64, 64, 64);
    conv3x3_cl<4, 2, true><<<512, blk, 0, stream>>>(sB, 64, sk1, st_u1, i4k, wm_u2, sA, st_u2, 128, 32, 128, 128);
    conv3x3_cl<4, 2, true><<<2048, blk, 0, stream>>>(sA, 32, sk0, st_u2, i16k, wm_u3, sB, st_u3, 64, 32, 256, 256);

    // ---- fused norm(u3) + 1x1 chain + residual + row FFT
    final_fft_rows<<<2048, 64, 0, stream>>>(sB, st_u3, i64k, x0, eff, cplx);

    // ---- FFT data consistency (cols fwd + combine + cols inv, rows inv)
    fft_cols_combine<<<2048, 64, 0, stream>>>(cplx, ksp, mask);
    fft_rows_inv<<<2048, 64, 0, stream>>>(cplx, (float*)d_out);
}

// Round 9
// 496.052 us; speedup vs baseline: 1.1684x; 1.0115x over previous
//
#include <hip/hip_runtime.h>

// ---------------------------------------------------------------------------
// UnetMACReconNet: modulated-conv UNet + IN/ReLU + FFT data consistency
// Round 9: u0 upsample re-materialized (fused-staging redundancy was 8x);
//          dense 1KB/instr stores via LDS-transpose in conv_d0 and all
//          conv3x3 variants whose output tile fits the dead s_x buffer.
// ---------------------------------------------------------------------------

#define EPS_IN 1e-5f

typedef __attribute__((ext_vector_type(8))) short short8;
typedef __attribute__((ext_vector_type(4))) short short4_t;
typedef __attribute__((ext_vector_type(4))) float f32x4;

__device__ __forceinline__ short f2bf(float f) {
    unsigned u = __float_as_uint(f);
    unsigned r = (u + 0x7fffu + ((u >> 16) & 1u)) >> 16;
    return (short)r;
}
__device__ __forceinline__ float bf2f(short s) {
    return __uint_as_float(((unsigned)(unsigned short)s) << 16);
}

// ---------------- zero the stat accumulators --------------------------------
__global__ void zero_f(float* __restrict__ p, int n)
{
    int i = blockIdx.x * 256 + threadIdx.x;
    if (i < n) p[i] = 0.f;
}

// ---------------- all-layer modded bf16 weights in one launch ---------------
struct WmJobs {
    const float* W[8];
    const float* mod[8];
    short* wm[8];
    int Co[8];
    int Ci[8];
    int cum[9];
};

__global__ void make_wm_all(WmJobs j)
{
    int idx = blockIdx.x * 256 + threadIdx.x;
    if (idx >= j.cum[8]) return;
    int l = 0;
    while (idx >= j.cum[l + 1]) ++l;
    int local = idx - j.cum[l];
    const int Ci = j.Ci[l], Co = j.Co[l];
    int ci = local % Ci;
    int rem = local / Ci;
    int co = rem % Co;
    int b = rem / Co;
    const float* wp = j.W[l] + (size_t)(co * Ci + ci) * 9;
    const float* mp = j.mod[l] + ((size_t)((size_t)b * Co + co) * Ci + ci) * 9;
    short* wm = j.wm[l];
#pragma unroll
    for (int k = 0; k < 9; ++k)
        wm[(((size_t)(b * 9 + k) * Co + co) * Ci + ci)] = f2bf(wp[k] * mp[k]);
}

// ---------------- MFMA conv3x3, CL, fused IN-stats; optional fused upsample -
template <int VR, int NCOG, bool UP>
__global__ __launch_bounds__(256) void conv3x3_cl(
    const short* __restrict__ x1, int Ci1,
    const short* __restrict__ x2,
    const float2* __restrict__ st1, float invHW1,
    const short* __restrict__ wm,   // [b][9][Co][Ci] bf16
    short* __restrict__ y,
    float2* __restrict__ stats,
    int Ci, int Co, int H, int W)
{
    constexpr int TH = 4 * VR, SH = TH + 2, SW = 18;
    constexpr int STN = UP ? 256 : 1;
    // dense-writeout staging fits in the (dead) s_x buffer?
    constexpr bool DW = (TH * 16 * NCOG * 16 * 2) <= (SH * SW * 32 * 2);
    __shared__ __align__(16) short s_x[SH][SW][32];
    __shared__ float s_red[4][4][NCOG][4][2];
    __shared__ float2 s_st1[STN];

    const int tid = threadIdx.x;
    const int lane = tid & 63, wv = tid >> 6;
    const int m = lane & 15, g = lane >> 4;

    const int b = blockIdx.x & 7;
    int r = blockIdx.x >> 3;
    const int nCoB = Co / (16 * NCOG);
    const int coblk = r % nCoB;
    const int tileId = r / nCoB;
    const int tilesx = W >> 4;
    const int tx0 = (tileId % tilesx) * 16;
    const int ty0 = (tileId / tilesx) * TH;
    const int co0 = coblk * (16 * NCOG);
    const int Ci2 = Ci - Ci1;
    const int Hs = H >> 1, Ws = W >> 1;

    if (UP) {
        for (int i = tid; i < Ci1; i += 256) {
            float2 v = st1[(size_t)b * Ci1 + i];
            float mu = v.x * invHW1;
            float var = v.y * invHW1 - mu * mu;
            s_st1[i] = make_float2(mu, rsqrtf(var + EPS_IN));
        }
    }

    f32x4 acc[NCOG][VR];
#pragma unroll
    for (int cg = 0; cg < NCOG; ++cg)
#pragma unroll
        for (int rr = 0; rr < VR; ++rr) acc[cg][rr] = (f32x4)0.f;

    const short* wmb = wm + (size_t)b * 9 * Co * Ci;
    const short* x1b = x1 + (size_t)b * (UP ? (size_t)Hs * Ws : (size_t)H * W) * Ci1;
    const short* x2b = x2 + (size_t)b * H * W * Ci2;

    for (int ci0 = 0; ci0 < Ci; ci0 += 32) {
        __syncthreads();
        if (UP && ci0 < Ci1) {
            const int cb = ci0;
            for (int idx = tid; idx < SH * SW * 4; idx += 256) {
                int gg = idx & 3, pos = idx >> 2;
                int yy = pos / SW, xx = pos - yy * SW;
                int gy = ty0 + yy - 1, gx = tx0 + xx - 1;
                short8 v = (short8)0;
                if (gy >= 0 && gy < H && gx >= 0 && gx < W) {
                    int xk = gx >> 1, yk = gy >> 1;
                    int xo = gx & 1, yo = gy & 1;
                    int xa = xo ? xk : (xk > 0 ? xk - 1 : 0);
                    int xb = xo ? (xk + 1 < Ws ? xk + 1 : Ws - 1) : xk;
                    float wxa = xo ? 0.75f : 0.25f;
                    int ya = yo ? yk : (yk > 0 ? yk - 1 : 0);
                    int yb = yo ? (yk + 1 < Hs ? yk + 1 : Hs - 1) : yk;
                    float wya = yo ? 0.75f : 0.25f;
                    const short* ib = x1b + cb + gg * 8;
                    short8 vaa = *(const short8*)(ib + ((size_t)ya * Ws + xa) * Ci1);
                    short8 vab = *(const short8*)(ib + ((size_t)ya * Ws + xb) * Ci1);
                    short8 vba = *(const short8*)(ib + ((size_t)yb * Ws + xa) * Ci1);
                    short8 vbb = *(const short8*)(ib + ((size_t)yb * Ws + xb) * Ci1);
#pragma unroll
                    for (int e = 0; e < 8; ++e) {
                        float2 sv = s_st1[cb + gg * 8 + e];
                        float aa = fmaxf(0.f, (bf2f(vaa[e]) - sv.x) * sv.y);
                        float ab = fmaxf(0.f, (bf2f(vab[e]) - sv.x) * sv.y);
                        float ba = fmaxf(0.f, (bf2f(vba[e]) - sv.x) * sv.y);
                        float bb = fmaxf(0.f, (bf2f(vbb[e]) - sv.x) * sv.y);
                        float r0 = wxa * aa + (1.f - wxa) * ab;
                        float r1 = wxa * ba + (1.f - wxa) * bb;
                        v[e] = f2bf(wya * r0 + (1.f - wya) * r1);
                    }
                }
                *(short8*)&s_x[yy][xx][(gg ^ (xx & 3)) * 8] = v;
            }
        } else {
            const short* src; int C, cb;
            if (ci0 < Ci1) { src = x1b; C = Ci1; cb = ci0; }
            else           { src = x2b; C = Ci2; cb = ci0 - Ci1; }
            for (int idx = tid; idx < SH * SW * 4; idx += 256) {
                int gg = idx & 3, pos = idx >> 2;
                int yy = pos / SW, xx = pos - yy * SW;
                int gy = ty0 + yy - 1, gx = tx0 + xx - 1;
                short8 v = (short8)0;
                if (gy >= 0 && gy < H && gx >= 0 && gx < W)
                    v = *(const short8*)(src + ((size_t)gy * W + gx) * C + cb + gg * 8);
                *(short8*)&s_x[yy][xx][(gg ^ (xx & 3)) * 8] = v;
            }
        }
        __syncthreads();
#pragma unroll
        for (int t = 0; t < 9; ++t) {
            const int dy = t / 3, dx = t - 3 * (t / 3);
            const short* wr = wmb + ((size_t)t * Co + co0) * Ci + ci0 + g * 8;
            short8 a[NCOG];
#pragma unroll
            for (int cg = 0; cg < NCOG; ++cg)
                a[cg] = *(const short8*)(wr + (size_t)(cg * 16 + m) * Ci);
            const int xx = m + dx;
            const int sgo = (g ^ (xx & 3)) * 8;
#pragma unroll
            for (int rr = 0; rr < VR; ++rr) {
                short8 bf = *(const short8*)&s_x[wv * VR + rr + dy][xx][sgo];
#pragma unroll
                for (int cg = 0; cg < NCOG; ++cg)
                    acc[cg][rr] = __builtin_amdgcn_mfma_f32_16x16x32_bf16(a[cg], bf, acc[cg][rr], 0, 0, 0);
            }
        }
    }

    // ---- writeout
    if constexpr (DW) {
        // stage output tile in (dead) s_x, then dense 16B x 64-lane stores
        __syncthreads();
        short* sd = (short*)&s_x[0][0][0];   // [TH][16][NCOG*16]
#pragma unroll
        for (int cg = 0; cg < NCOG; ++cg)
#pragma unroll
            for (int rr = 0; rr < VR; ++rr) {
                short4_t o;
#pragma unroll
                for (int q = 0; q < 4; ++q) o[q] = f2bf(acc[cg][rr][q]);
                *(short4_t*)&sd[((wv * VR + rr) * 16 + m) * (NCOG * 16) + cg * 16 + g * 4] = o;
            }
        __syncthreads();
        constexpr int N16 = TH * 16 * NCOG * 2;       // 16B chunks in tile
        constexpr int CPR = NCOG * 32;                // chunks per row
        for (int c = tid; c < N16; c += 256) {
            int row = c / CPR;
            int o16 = c % CPR;
            int p = o16 / (NCOG * 2);
            int cw = o16 % (NCOG * 2);
            short8 v = *(short8*)&sd[(row * 16 + p) * (NCOG * 16) + cw * 8];
            *(short8*)(y + (((size_t)b * H + ty0 + row) * W + tx0 + p) * Co + co0 + cw * 8) = v;
        }
    } else {
        const int ox = tx0 + m;
#pragma unroll
        for (int cg = 0; cg < NCOG; ++cg)
#pragma unroll
            for (int rr = 0; rr < VR; ++rr) {
                int oy = ty0 + wv * VR + rr;
                short4_t o;
#pragma unroll
                for (int q = 0; q < 4; ++q) o[q] = f2bf(acc[cg][rr][q]);
                *(short4_t*)(y + (((size_t)b * H + oy) * W + ox) * Co + co0 + cg * 16 + g * 4) = o;
            }
    }

    // ---- fused stats
#pragma unroll
    for (int cg = 0; cg < NCOG; ++cg)
#pragma unroll
        for (int q = 0; q < 4; ++q) {
            float s = 0.f, s2 = 0.f;
#pragma unroll
            for (int rr = 0; rr < VR; ++rr) { float v = acc[cg][rr][q]; s += v; s2 += v * v; }
#pragma unroll
            for (int msk = 1; msk < 16; msk <<= 1) { s += __shfl_xor(s, msk); s2 += __shfl_xor(s2, msk); }
            if (m == 0) { s_red[wv][g][cg][q][0] = s; s_red[wv][g][cg][q][1] = s2; }
        }
    __syncthreads();
    for (int i = tid; i < 16 * NCOG; i += 256) {
        int q = i & 3, gg = (i >> 2) & 3, cg = i >> 4;
        float S = 0.f, S2 = 0.f;
#pragma unroll
        for (int w = 0; w < 4; ++w) { S += s_red[w][gg][cg][q][0]; S2 += s_red[w][gg][cg][q][1]; }
        float* sp = (float*)&stats[(size_t)b * Co + co0 + i];
        atomicAdd(sp, S); atomicAdd(sp + 1, S2);
    }
}

// ---------------- d0 conv: Ci=1, Co=32, fp32 NCHW in -> CL bf16 raw out -----
__global__ __launch_bounds__(256) void conv_d0_cl(
    const float* __restrict__ x0, const float* __restrict__ W,
    const float* __restrict__ mod, short* __restrict__ y,
    float2* __restrict__ stats)
{
    __shared__ float s[18][18];
    __shared__ float sw[32][9];
    __shared__ float s_red[4][32][2];
    __shared__ __align__(16) short sd[16][16][32];   // output staging (16KB)
    const int tid = threadIdx.x;
    const int tx = tid & 15, ty = tid >> 4;
    const int tx0 = (blockIdx.x & 15) * 16, ty0 = (blockIdx.x >> 4) * 16;
    const int b = blockIdx.y;
    if (tid < 288) sw[tid / 9][tid % 9] = W[tid] * mod[b * 288 + tid];
    for (int pos = tid; pos < 18 * 18; pos += 256) {
        int yy = pos / 18, xx = pos - yy * 18;
        int gy = ty0 + yy - 1, gx = tx0 + xx - 1;
        bool inb = gy >= 0 && gy < 256 && gx >= 0 && gx < 256;
        s[yy][xx] = inb ? x0[((size_t)b << 16) + gy * 256 + gx] : 0.f;
    }
    __syncthreads();
    float v[3][3];
#pragma unroll
    for (int r = 0; r < 3; ++r)
#pragma unroll
        for (int c = 0; c < 3; ++c) v[r][c] = s[ty + r][tx + c];
    float vals[32];
#pragma unroll
    for (int co = 0; co < 32; ++co) {
        float a = 0.f;
#pragma unroll
        for (int r = 0; r < 3; ++r)
#pragma unroll
            for (int c = 0; c < 3; ++c) a = fmaf(v[r][c], sw[co][r * 3 + c], a);
        vals[co] = a;
    }
#pragma unroll
    for (int j = 0; j < 4; ++j) {
        short8 o;
#pragma unroll
        for (int e = 0; e < 8; ++e) o[e] = f2bf(vals[j * 8 + e]);
        *(short8*)&sd[ty][tx][j * 8] = o;
    }
    const int lane = tid & 63, wv = tid >> 6;
#pragma unroll
    for (int co = 0; co < 32; ++co) {
        float sm = vals[co], s2 = vals[co] * vals[co];
#pragma unroll
        for (int off = 32; off > 0; off >>= 1) { sm += __shfl_down(sm, off); s2 += __shfl_down(s2, off); }
        if (lane == 0) { s_red[wv][co][0] = sm; s_red[wv][co][1] = s2; }
    }
    __syncthreads();
    // dense stores: row = 16 px * 64B = 1KB contiguous per 64 chunks
    for (int c = tid; c < 1024; c += 256) {
        int row = c >> 6, o = c & 63;
        short8 vv = *(short8*)&sd[row][o >> 2][(o & 3) * 8];
        *(short8*)(y + (((size_t)b * 256 + ty0 + row) * 256 + tx0 + (o >> 2)) * 32 + (o & 3) * 8) = vv;
    }
    if (tid < 32) {
        float S = 0.f, S2 = 0.f;
#pragma unroll
        for (int w = 0; w < 4; ++w) { S += s_red[w][tid][0]; S2 += s_red[w][tid][1]; }
        float* sp = (float*)&stats[(size_t)b * 32 + tid];
        atomicAdd(sp, S); atomicAdd(sp + 1, S2);
    }
}

// ---------------- 2x2 maxpool + fused norm/relu + normalized skip writeback -
__global__ void maxpool_cl(short* __restrict__ in,
                           const float2* __restrict__ st, float invHW,
                           short* __restrict__ out,
                           int c8s, int ws, int hs, int total8)
{
    const int C = 8 << c8s;
    for (int idx = blockIdx.x * 256 + threadIdx.x; idx < total8; idx += gridDim.x * 256) {
        int c8 = idx & ((1 << c8s) - 1);
        int p = idx >> c8s;
        int x = p & ((1 << ws) - 1);
        int yy = (p >> ws) & ((1 << hs) - 1);
        int b = p >> (ws + hs);
        short* ip = in + (((size_t)b * (2 << hs) + 2 * yy) * (2 << ws) + 2 * x) * C + c8 * 8;
        size_t rs = (size_t)(2 << ws) * C;
        short8 v0 = *(const short8*)ip, v1 = *(const short8*)(ip + C);
        short8 v2 = *(const short8*)(ip + rs), v3 = *(const short8*)(ip + rs + C);
        short8 o, w0, w1, w2, w3;
#pragma unroll
        for (int e = 0; e < 8; ++e) {
            float2 sv = st[(size_t)b * C + c8 * 8 + e];
            float mu = sv.x * invHW;
            float rsig = rsqrtf(sv.y * invHW - mu * mu + EPS_IN);
            float n0 = fmaxf(0.f, (bf2f(v0[e]) - mu) * rsig);
            float n1 = fmaxf(0.f, (bf2f(v1[e]) - mu) * rsig);
            float n2 = fmaxf(0.f, (bf2f(v2[e]) - mu) * rsig);
            float n3 = fmaxf(0.f, (bf2f(v3[e]) - mu) * rsig);
            w0[e] = f2bf(n0); w1[e] = f2bf(n1); w2[e] = f2bf(n2); w3[e] = f2bf(n3);
            o[e] = f2bf(fmaxf(fmaxf(n0, n1), fmaxf(n2, n3)));
        }
        *(short8*)ip = w0;
        *(short8*)(ip + C) = w1;
        *(short8*)(ip + rs) = w2;
        *(short8*)(ip + rs + C) = w3;
        *(short8*)(out + (size_t)idx * 8) = o;
    }
}

// ---------------- bilinear 2x upsample + fused norm/relu (u0 source only) ---
__global__ void upsample_cl(const short* __restrict__ in,
                            const float2* __restrict__ st, float invHW,
                            short* __restrict__ out,
                            int c8s, int wsi, int hsi, int total8)
{
    const int C = 8 << c8s;
    const int Win = 1 << wsi, Hin = 1 << hsi;
    for (int idx = blockIdx.x * 256 + threadIdx.x; idx < total8; idx += gridDim.x * 256) {
        int c8 = idx & ((1 << c8s) - 1);
        int p = idx >> c8s;
        int x = p & (2 * Win - 1);
        int yy = (p >> (wsi + 1)) & (2 * Hin - 1);
        int b = p >> (wsi + 1 + hsi + 1);
        int xk = x >> 1, yk = yy >> 1;
        int xa, xb; float wxa;
        if (x & 1) { xa = xk; xb = (xk + 1 < Win) ? xk + 1 : Win - 1; wxa = 0.75f; }
        else       { xa = (xk > 0) ? xk - 1 : 0; xb = xk; wxa = 0.25f; }
        int ya, yb; float wya;
        if (yy & 1) { ya = yk; yb = (yk + 1 < Hin) ? yk + 1 : Hin - 1; wya = 0.75f; }
        else        { ya = (yk > 0) ? yk - 1 : 0; yb = yk; wya = 0.25f; }
        const short* ib = in + (size_t)b * Hin * Win * C + c8 * 8;
        short8 vaa = *(const short8*)(ib + ((size_t)ya * Win + xa) * C);
        short8 vab = *(const short8*)(ib + ((size_t)ya * Win + xb) * C);
        short8 vba = *(const short8*)(ib + ((size_t)yb * Win + xa) * C);
        short8 vbb = *(const short8*)(ib + ((size_t)yb * Win + xb) * C);
        short8 o;
#pragma unroll
        for (int e = 0; e < 8; ++e) {
            float2 sv = st[(size_t)b * C + c8 * 8 + e];
            float mu = sv.x * invHW;
            float rsig = rsqrtf(sv.y * invHW - mu * mu + EPS_IN);
            float aa = fmaxf(0.f, (bf2f(vaa[e]) - mu) * rsig);
            float ab = fmaxf(0.f, (bf2f(vab[e]) - mu) * rsig);
            float ba = fmaxf(0.f, (bf2f(vba[e]) - mu) * rsig);
            float bb = fmaxf(0.f, (bf2f(vbb[e]) - mu) * rsig);
            float r0 = wxa * aa + (1.f - wxa) * ab;
            float r1 = wxa * ba + (1.f - wxa) * bb;
            o[e] = f2bf(wya * r0 + (1.f - wya) * r1);
        }
        *(short8*)(out + (size_t)idx * 8) = o;
    }
}

// ---------------- compose the three 1x1 convs into one 32->1 map ------------
__global__ void eff1x1(const float* __restrict__ w1, const float* __restrict__ b1,
                       const float* __restrict__ w2, const float* __restrict__ b2,
                       const float* __restrict__ w3, const float* __restrict__ b3,
                       float* __restrict__ eff)
{
    int t = threadIdx.x;
    if (t < 32) {
        float s = 0.f;
        for (int k = 0; k < 16; ++k) s += w2[k] * w1[k * 32 + t];
        eff[t] = w3[0] * s;
    }
    if (t == 32) {
        float s = 0.f;
        for (int k = 0; k < 16; ++k) s += w2[k] * b1[k];
        eff[32] = w3[0] * (s + b2[0]) + b3[0];
    }
}

// ---------------- 256-point radix-2 FFT in LDS (one wave) -------------------
__device__ __forceinline__ void fft256(float2* s, int tid, float sign)
{
    __syncthreads();
#pragma unroll
    for (int t = 0; t < 4; ++t) {
        int i = tid + t * 64;
        int r = __brev(i) >> 24;
        if (r > i) { float2 tmp = s[i]; s[i] = s[r]; s[r] = tmp; }
    }
    __syncthreads();
    for (int st = 1; st <= 8; ++st) {
        int m = 1 << st, half = m >> 1;
#pragma unroll
        for (int t = 0; t < 2; ++t) {
            int k = tid + t * 64;
            int g = k >> (st - 1), j = k & (half - 1);
            int i0 = (g << st) + j, i1 = i0 + half;
            float ang = sign * 6.283185307179586f * (float)j / (float)m;
            float sn, cs;
            __sincosf(ang, &sn, &cs);
            float2 a = s[i0], b = s[i1];
            float2 tt = make_float2(b.x * cs - b.y * sn, b.x * sn + b.y * cs);
            s[i0] = make_float2(a.x + tt.x, a.y + tt.y);
            s[i1] = make_float2(a.x - tt.x, a.y - tt.y);
        }
        __syncthreads();
    }
}

// ---------------- fused: norm(u3) + 1x1 chain + residual + row FFT ----------
__global__ __launch_bounds__(64) void final_fft_rows(
    const short* __restrict__ act, const float2* __restrict__ st, float invHW,
    const float* __restrict__ x0, const float* __restrict__ eff,
    float2* __restrict__ cplx)
{
    __shared__ float2 s[256];
    __shared__ float2 sst[32];
    __shared__ float seff[33];
    const int row = blockIdx.x, tid = threadIdx.x;
    const int b = row >> 8, yy = row & 255;
    if (tid < 32) {
        float2 v = st[(size_t)b * 32 + tid];
        float mu = v.x * invHW;
        sst[tid] = make_float2(mu, rsqrtf(v.y * invHW - mu * mu + EPS_IN));
    }
    if (tid < 33) seff[tid] = eff[tid];
    __syncthreads();
#pragma unroll
    for (int k = 0; k < 4; ++k) {
        int x = k * 64 + tid;
        const short8* a = (const short8*)(act + (((size_t)b * 256 + yy) * 256 + x) * 32);
        float sacc = seff[32] + x0[((size_t)b << 16) + (yy << 8) + x];
#pragma unroll
        for (int j = 0; j < 4; ++j) {
            short8 v = a[j];
#pragma unroll
            for (int e = 0; e < 8; ++e) {
                float2 sv = sst[j * 8 + e];
                sacc += seff[j * 8 + e] * fmaxf(0.f, (bf2f(v[e]) - sv.x) * sv.y);
            }
        }
        s[x] = make_float2(sacc, 0.f);
    }
    fft256(s, tid, -1.f);
    float2* o = cplx + (size_t)row * 256;
    for (int i = tid; i < 256; i += 64) o[i] = s[i];
}

__global__ __launch_bounds__(64) void fft_cols_combine(float2* __restrict__ data,
                                                       const float* __restrict__ ksp,
                                                       const float* __restrict__ mask)
{
    __shared__ float2 s[256];
    int col = blockIdx.x & 255, b = blockIdx.x >> 8;
    int tid = threadIdx.x;
    float2* base = data + (size_t)b * 65536 + col;
    for (int i = tid; i < 256; i += 64) s[i] = base[(size_t)i * 256];
    fft256(s, tid, -1.f);
    for (int i = tid; i < 256; i += 64) {
        size_t mi = ((size_t)b * 256 + i) * 256 + col;
        float m = mask[mi];
        float2 kp = s[i];
        float kr = ksp[mi * 2], ki = ksp[mi * 2 + 1];
        s[i] = make_float2(m * kr + (1.f - m) * kp.x * (1.f / 256.f),
                           m * ki + (1.f - m) * kp.y * (1.f / 256.f));
    }
    fft256(s, tid, 1.f);
    for (int i = tid; i < 256; i += 64) base[(size_t)i * 256] = s[i];
}

__global__ __launch_bounds__(64) void fft_rows_inv(const float2* __restrict__ data,
                                                   float* __restrict__ out)
{
    __shared__ float2 s[256];
    int row = blockIdx.x, tid = threadIdx.x;
    const float2* p = data + (size_t)row * 256;
    for (int i = tid; i < 256; i += 64) s[i] = p[i];
    fft256(s, tid, 1.f);
    float* o = out + (size_t)row * 256;
    for (int i = tid; i < 256; i += 64) o[i] = s[i].x * (1.f / 256.f);
}

// ---------------------------------------------------------------------------
extern "C" void kernel_launch(void* const* d_in, const int* in_sizes, int n_in,
                              void* d_out, int out_size, void* d_ws, size_t ws_size,
                              hipStream_t stream)
{
    (void)in_sizes; (void)n_in; (void)out_size; (void)ws_size;

    const float* x0 = (const float*)d_in[0];
    const float* ksp = (const float*)d_in[1];
    const float* mask = (const float*)d_in[2];
    const float* mod_d[4] = {(const float*)d_in[3], (const float*)d_in[6],
                             (const float*)d_in[9], (const float*)d_in[12]};
    const float* W_d[4] = {(const float*)d_in[4], (const float*)d_in[7],
                           (const float*)d_in[10], (const float*)d_in[13]};
    const float* mod_lat = (const float*)d_in[15];
    const float* W_lat = (const float*)d_in[16];
    const float* mod_u[4] = {(const float*)d_in[18], (const float*)d_in[21],
                             (const float*)d_in[24], (const float*)d_in[27]};
    const float* W_u[4] = {(const float*)d_in[19], (const float*)d_in[22],
                           (const float*)d_in[25], (const float*)d_in[28]};
    const float* w_c1 = (const float*)d_in[30];
    const float* b_c1 = (const float*)d_in[31];
    const float* w_c2 = (const float*)d_in[32];
    const float* b_c2 = (const float*)d_in[33];
    const float* w_c3 = (const float*)d_in[34];
    const float* b_c3 = (const float*)d_in[35];

    // ---- workspace layout (CL bf16 activations), ~165 MB
    short* sA  = (short*)d_ws;          // 16,777,216
    short* sB  = sA + 16777216;         // 16,777,216
    short* sk0 = sB + 16777216;         // 16,777,216 (8,256,256,32)
    short* sk1 = sk0 + 16777216;        //  8,388,608 (8,128,128,64)
    short* sk2 = sk1 + 8388608;         //  4,194,304 (8,64,64,128)
    short* sk3 = sk2 + 4194304;         //  2,097,152 (8,32,32,256)
    short* wm_d1 = sk3 + 2097152;       //    147,456
    short* wm_d2 = wm_d1 + 147456;      //    589,824
    short* wm_d3 = wm_d2 + 589824;      //  2,359,296
    short* wm_lat = wm_d3 + 2359296;    //  4,718,592
    short* wm_u0 = wm_lat + 4718592;    //  4,718,592
    short* wm_u1 = wm_u0 + 4718592;     //  1,179,648
    short* wm_u2 = wm_u1 + 1179648;     //    294,912
    short* wm_u3 = wm_u2 + 294912;      //    147,456
    float2* cplx = (float2*)(wm_u3 + 147456);  // 524,288 float2
    float2* stA = cplx + 524288;               // 7,936 float2 stat accumulators
    float* eff = (float*)(stA + 7936);         // 64

    // per-layer stat slices
    float2* st_d0 = stA + 0;
    float2* st_d1 = stA + 256;
    float2* st_d2 = stA + 768;
    float2* st_d3 = stA + 1792;
    float2* st_lat = stA + 3840;
    float2* st_u0 = stA + 5888;
    float2* st_u1 = stA + 6912;
    float2* st_u2 = stA + 7424;
    float2* st_u3 = stA + 7680;

    const float i64k = 1.f / 65536.f, i16k = 1.f / 16384.f, i4k = 1.f / 4096.f,
                i1k = 1.f / 1024.f, i256 = 1.f / 256.f;

    dim3 blk(256);

    zero_f<<<62, blk, 0, stream>>>((float*)stA, 15872);
    eff1x1<<<1, 64, 0, stream>>>(w_c1, b_c1, w_c2, b_c2, w_c3, b_c3, eff);

    // ---- all modded weights, one launch
    WmJobs jobs;
    const float* Wl[8]  = {W_d[1], W_d[2], W_d[3], W_lat, W_u[0], W_u[1], W_u[2], W_u[3]};
    const float* Ml[8]  = {mod_d[1], mod_d[2], mod_d[3], mod_lat, mod_u[0], mod_u[1], mod_u[2], mod_u[3]};
    short* WMl[8] = {wm_d1, wm_d2, wm_d3, wm_lat, wm_u0, wm_u1, wm_u2, wm_u3};
    int Col[8] = {64, 128, 256, 256, 128, 64, 32, 32};
    int Cil[8] = {32, 64, 128, 256, 512, 256, 128, 64};
    jobs.cum[0] = 0;
    for (int l = 0; l < 8; ++l) {
        jobs.W[l] = Wl[l]; jobs.mod[l] = Ml[l]; jobs.wm[l] = WMl[l];
        jobs.Co[l] = Col[l]; jobs.Ci[l] = Cil[l];
        jobs.cum[l + 1] = jobs.cum[l] + 8 * Col[l] * Cil[l];
    }
    make_wm_all<<<(jobs.cum[8] + 255) / 256, blk, 0, stream>>>(jobs);

    // ---- down path
    conv_d0_cl<<<dim3(256, 8), blk, 0, stream>>>(x0, W_d[0], mod_d[0], sk0, st_d0);
    maxpool_cl<<<2048, blk, 0, stream>>>(sk0, st_d0, i64k, sA, 2, 7, 7, 524288);

    conv3x3_cl<4, 4, false><<<512, blk, 0, stream>>>(sA, 32, sA, stA, 0.f, wm_d1, sk1, st_d1, 32, 64, 128, 128);
    maxpool_cl<<<1024, blk, 0, stream>>>(sk1, st_d1, i16k, sA, 3, 6, 6, 262144);

    conv3x3_cl<2, 4, false><<<512, blk, 0, stream>>>(sA, 64, sA, stA, 0.f, wm_d2, sk2, st_d2, 64, 128, 64, 64);
    maxpool_cl<<<512, blk, 0, stream>>>(sk2, st_d2, i4k, sA, 4, 5, 5, 131072);

    conv3x3_cl<2, 2, false><<<512, blk, 0, stream>>>(sA, 128, sA, stA, 0.f, wm_d3, sk3, st_d3, 128, 256, 32, 32);
    maxpool_cl<<<256, blk, 0, stream>>>(sk3, st_d3, i1k, sA, 5, 4, 4, 65536);

    conv3x3_cl<2, 1, false><<<256, blk, 0, stream>>>(sA, 256, sA, stA, 0.f, wm_lat, sB, st_lat, 256, 256, 16, 16);

    // ---- up path
    // u0: materialize norm+upsample of latent (tiny, L2-hot), then plain conv
    upsample_cl<<<1024, blk, 0, stream>>>(sB, st_lat, i256, sA, 5, 4, 4, 262144);
    conv3x3_cl<2, 1, false><<<512, blk, 0, stream>>>(sA, 256, sk3, stA, 0.f, wm_u0, sB, st_u0, 512, 128, 32, 32);
    // u1..u3: bilinear+norm fused into conv staging (x1 = raw low-res)
    conv3x3_cl<2, 2, true><<<512, blk, 0, stream>>>(sB, 128, sk2, st_u0, i1k, wm_u1, sA, st_u1, 256, 64, 64, 64);
    conv3x3_cl<4, 2, true><<<512, blk, 0, stream>>>(sA, 64, sk1, st_u1, i4k, wm_u2, sB, st_u2, 128, 32, 128, 128);
    conv3x3_cl<4, 2, true><<<2048, blk, 0, stream>>>(sB, 32, sk0, st_u2, i16k, wm_u3, sA, st_u3, 64, 32, 256, 256);

    // ---- fused norm(u3) + 1x1 chain + residual + row FFT
    final_fft_rows<<<2048, 64, 0, stream>>>(sA, st_u3, i64k, x0, eff, cplx);

    // ---- FFT data consistency
    fft_cols_combine<<<2048, 64, 0, stream>>>(cplx, ksp, mask);
    fft_rows_inv<<<2048, 64, 0, stream>>>(cplx, (float*)d_out);
}

// Round 10
// 471.313 us; speedup vs baseline: 1.2297x; 1.0525x over previous
//
#include <hip/hip_runtime.h>

// ---------------------------------------------------------------------------
// UnetMACReconNet: modulated-conv UNet + IN/ReLU + FFT data consistency
// Round 10: conv_d0 stat epilogue via LDS-transpose reads (no 384-shfl chain);
//           all stat atomics bucketed 8-way (consumers sum buckets once).
// ---------------------------------------------------------------------------

#define EPS_IN 1e-5f
constexpr int STST = 7936;   // float2 stride between stat buckets

typedef __attribute__((ext_vector_type(8))) short short8;
typedef __attribute__((ext_vector_type(4))) short short4_t;
typedef __attribute__((ext_vector_type(4))) float f32x4;

__device__ __forceinline__ short f2bf(float f) {
    unsigned u = __float_as_uint(f);
    unsigned r = (u + 0x7fffu + ((u >> 16) & 1u)) >> 16;
    return (short)r;
}
__device__ __forceinline__ float bf2f(short s) {
    return __uint_as_float(((unsigned)(unsigned short)s) << 16);
}

// ---------------- zero the stat accumulators --------------------------------
__global__ void zero_f(float* __restrict__ p, int n)
{
    int i = blockIdx.x * 256 + threadIdx.x;
    if (i < n) p[i] = 0.f;
}

// ---------------- all-layer modded bf16 weights in one launch ---------------
struct WmJobs {
    const float* W[8];
    const float* mod[8];
    short* wm[8];
    int Co[8];
    int Ci[8];
    int cum[9];
};

__global__ void make_wm_all(WmJobs j)
{
    int idx = blockIdx.x * 256 + threadIdx.x;
    if (idx >= j.cum[8]) return;
    int l = 0;
    while (idx >= j.cum[l + 1]) ++l;
    int local = idx - j.cum[l];
    const int Ci = j.Ci[l], Co = j.Co[l];
    int ci = local % Ci;
    int rem = local / Ci;
    int co = rem % Co;
    int b = rem / Co;
    const float* wp = j.W[l] + (size_t)(co * Ci + ci) * 9;
    const float* mp = j.mod[l] + ((size_t)((size_t)b * Co + co) * Ci + ci) * 9;
    short* wm = j.wm[l];
#pragma unroll
    for (int k = 0; k < 9; ++k)
        wm[(((size_t)(b * 9 + k) * Co + co) * Ci + ci)] = f2bf(wp[k] * mp[k]);
}

// ---------------- MFMA conv3x3, CL, fused IN-stats; optional fused upsample -
template <int VR, int NCOG, bool UP>
__global__ __launch_bounds__(256) void conv3x3_cl(
    const short* __restrict__ x1, int Ci1,
    const short* __restrict__ x2,
    const float2* __restrict__ st1, float invHW1,
    const short* __restrict__ wm,   // [b][9][Co][Ci] bf16
    short* __restrict__ y,
    float2* __restrict__ stats,
    int Ci, int Co, int H, int W)
{
    constexpr int TH = 4 * VR, SH = TH + 2, SW = 18;
    constexpr int STN = UP ? 256 : 1;
    constexpr bool DW = (TH * 16 * NCOG * 16 * 2) <= (SH * SW * 32 * 2);
    __shared__ __align__(16) short s_x[SH][SW][32];
    __shared__ float s_red[4][4][NCOG][4][2];
    __shared__ float2 s_st1[STN];

    const int tid = threadIdx.x;
    const int lane = tid & 63, wv = tid >> 6;
    const int m = lane & 15, g = lane >> 4;

    const int b = blockIdx.x & 7;
    int r = blockIdx.x >> 3;
    const int nCoB = Co / (16 * NCOG);
    const int coblk = r % nCoB;
    const int tileId = r / nCoB;
    const int tilesx = W >> 4;
    const int tx0 = (tileId % tilesx) * 16;
    const int ty0 = (tileId / tilesx) * TH;
    const int co0 = coblk * (16 * NCOG);
    const int Ci2 = Ci - Ci1;
    const int Hs = H >> 1, Ws = W >> 1;
    const int bucket = tileId & 7;

    if (UP) {
        for (int i = tid; i < Ci1; i += 256) {
            float sx = 0.f, sy = 0.f;
#pragma unroll
            for (int k = 0; k < 8; ++k) {
                float2 v = st1[(size_t)k * STST + (size_t)b * Ci1 + i];
                sx += v.x; sy += v.y;
            }
            float mu = sx * invHW1;
            float var = sy * invHW1 - mu * mu;
            s_st1[i] = make_float2(mu, rsqrtf(var + EPS_IN));
        }
    }

    f32x4 acc[NCOG][VR];
#pragma unroll
    for (int cg = 0; cg < NCOG; ++cg)
#pragma unroll
        for (int rr = 0; rr < VR; ++rr) acc[cg][rr] = (f32x4)0.f;

    const short* wmb = wm + (size_t)b * 9 * Co * Ci;
    const short* x1b = x1 + (size_t)b * (UP ? (size_t)Hs * Ws : (size_t)H * W) * Ci1;
    const short* x2b = x2 + (size_t)b * H * W * Ci2;

    for (int ci0 = 0; ci0 < Ci; ci0 += 32) {
        __syncthreads();
        if (UP && ci0 < Ci1) {
            const int cb = ci0;
            for (int idx = tid; idx < SH * SW * 4; idx += 256) {
                int gg = idx & 3, pos = idx >> 2;
                int yy = pos / SW, xx = pos - yy * SW;
                int gy = ty0 + yy - 1, gx = tx0 + xx - 1;
                short8 v = (short8)0;
                if (gy >= 0 && gy < H && gx >= 0 && gx < W) {
                    int xk = gx >> 1, yk = gy >> 1;
                    int xo = gx & 1, yo = gy & 1;
                    int xa = xo ? xk : (xk > 0 ? xk - 1 : 0);
                    int xb = xo ? (xk + 1 < Ws ? xk + 1 : Ws - 1) : xk;
                    float wxa = xo ? 0.75f : 0.25f;
                    int ya = yo ? yk : (yk > 0 ? yk - 1 : 0);
                    int yb = yo ? (yk + 1 < Hs ? yk + 1 : Hs - 1) : yk;
                    float wya = yo ? 0.75f : 0.25f;
                    const short* ib = x1b + cb + gg * 8;
                    short8 vaa = *(const short8*)(ib + ((size_t)ya * Ws + xa) * Ci1);
                    short8 vab = *(const short8*)(ib + ((size_t)ya * Ws + xb) * Ci1);
                    short8 vba = *(const short8*)(ib + ((size_t)yb * Ws + xa) * Ci1);
                    short8 vbb = *(const short8*)(ib + ((size_t)yb * Ws + xb) * Ci1);
#pragma unroll
                    for (int e = 0; e < 8; ++e) {
                        float2 sv = s_st1[cb + gg * 8 + e];
                        float aa = fmaxf(0.f, (bf2f(vaa[e]) - sv.x) * sv.y);
                        float ab = fmaxf(0.f, (bf2f(vab[e]) - sv.x) * sv.y);
                        float ba = fmaxf(0.f, (bf2f(vba[e]) - sv.x) * sv.y);
                        float bb = fmaxf(0.f, (bf2f(vbb[e]) - sv.x) * sv.y);
                        float r0 = wxa * aa + (1.f - wxa) * ab;
                        float r1 = wxa * ba + (1.f - wxa) * bb;
                        v[e] = f2bf(wya * r0 + (1.f - wya) * r1);
                    }
                }
                *(short8*)&s_x[yy][xx][(gg ^ (xx & 3)) * 8] = v;
            }
        } else {
            const short* src; int C, cb;
            if (ci0 < Ci1) { src = x1b; C = Ci1; cb = ci0; }
            else           { src = x2b; C = Ci2; cb = ci0 - Ci1; }
            for (int idx = tid; idx < SH * SW * 4; idx += 256) {
                int gg = idx & 3, pos = idx >> 2;
                int yy = pos / SW, xx = pos - yy * SW;
                int gy = ty0 + yy - 1, gx = tx0 + xx - 1;
                short8 v = (short8)0;
                if (gy >= 0 && gy < H && gx >= 0 && gx < W)
                    v = *(const short8*)(src + ((size_t)gy * W + gx) * C + cb + gg * 8);
                *(short8*)&s_x[yy][xx][(gg ^ (xx & 3)) * 8] = v;
            }
        }
        __syncthreads();
#pragma unroll
        for (int t = 0; t < 9; ++t) {
            const int dy = t / 3, dx = t - 3 * (t / 3);
            const short* wr = wmb + ((size_t)t * Co + co0) * Ci + ci0 + g * 8;
            short8 a[NCOG];
#pragma unroll
            for (int cg = 0; cg < NCOG; ++cg)
                a[cg] = *(const short8*)(wr + (size_t)(cg * 16 + m) * Ci);
            const int xx = m + dx;
            const int sgo = (g ^ (xx & 3)) * 8;
#pragma unroll
            for (int rr = 0; rr < VR; ++rr) {
                short8 bf = *(const short8*)&s_x[wv * VR + rr + dy][xx][sgo];
#pragma unroll
                for (int cg = 0; cg < NCOG; ++cg)
                    acc[cg][rr] = __builtin_amdgcn_mfma_f32_16x16x32_bf16(a[cg], bf, acc[cg][rr], 0, 0, 0);
            }
        }
    }

    // ---- writeout
    if constexpr (DW) {
        __syncthreads();
        short* sd = (short*)&s_x[0][0][0];   // [TH][16][NCOG*16]
#pragma unroll
        for (int cg = 0; cg < NCOG; ++cg)
#pragma unroll
            for (int rr = 0; rr < VR; ++rr) {
                short4_t o;
#pragma unroll
                for (int q = 0; q < 4; ++q) o[q] = f2bf(acc[cg][rr][q]);
                *(short4_t*)&sd[((wv * VR + rr) * 16 + m) * (NCOG * 16) + cg * 16 + g * 4] = o;
            }
        __syncthreads();
        constexpr int N16 = TH * 16 * NCOG * 2;
        constexpr int CPR = NCOG * 32;
        for (int c = tid; c < N16; c += 256) {
            int row = c / CPR;
            int o16 = c % CPR;
            int p = o16 / (NCOG * 2);
            int cw = o16 % (NCOG * 2);
            short8 v = *(short8*)&sd[(row * 16 + p) * (NCOG * 16) + cw * 8];
            *(short8*)(y + (((size_t)b * H + ty0 + row) * W + tx0 + p) * Co + co0 + cw * 8) = v;
        }
    } else {
        const int ox = tx0 + m;
#pragma unroll
        for (int cg = 0; cg < NCOG; ++cg)
#pragma unroll
            for (int rr = 0; rr < VR; ++rr) {
                int oy = ty0 + wv * VR + rr;
                short4_t o;
#pragma unroll
                for (int q = 0; q < 4; ++q) o[q] = f2bf(acc[cg][rr][q]);
                *(short4_t*)(y + (((size_t)b * H + oy) * W + ox) * Co + co0 + cg * 16 + g * 4) = o;
            }
    }

    // ---- fused stats (bucketed atomics)
#pragma unroll
    for (int cg = 0; cg < NCOG; ++cg)
#pragma unroll
        for (int q = 0; q < 4; ++q) {
            float s = 0.f, s2 = 0.f;
#pragma unroll
            for (int rr = 0; rr < VR; ++rr) { float v = acc[cg][rr][q]; s += v; s2 += v * v; }
#pragma unroll
            for (int msk = 1; msk < 16; msk <<= 1) { s += __shfl_xor(s, msk); s2 += __shfl_xor(s2, msk); }
            if (m == 0) { s_red[wv][g][cg][q][0] = s; s_red[wv][g][cg][q][1] = s2; }
        }
    __syncthreads();
    for (int i = tid; i < 16 * NCOG; i += 256) {
        int q = i & 3, gg = (i >> 2) & 3, cg = i >> 4;
        float S = 0.f, S2 = 0.f;
#pragma unroll
        for (int w = 0; w < 4; ++w) { S += s_red[w][gg][cg][q][0]; S2 += s_red[w][gg][cg][q][1]; }
        float* sp = (float*)&stats[(size_t)bucket * STST + (size_t)b * Co + co0 + i];
        atomicAdd(sp, S); atomicAdd(sp + 1, S2);
    }
}

// ---------------- d0 conv: Ci=1, Co=32, fp32 NCHW in -> CL bf16 raw out -----
// Stats via LDS-transpose reads of the staged output tile (no shfl chain).
__global__ __launch_bounds__(256) void conv_d0_cl(
    const float* __restrict__ x0, const float* __restrict__ W,
    const float* __restrict__ mod, short* __restrict__ y,
    float2* __restrict__ stats)
{
    __shared__ float s[18][18];
    __shared__ float sw[32][9];
    __shared__ float s_red[8][32][2];
    __shared__ __align__(16) short sd[16][16][32];
    const int tid = threadIdx.x;
    const int tx = tid & 15, ty = tid >> 4;
    const int tx0 = (blockIdx.x & 15) * 16, ty0 = (blockIdx.x >> 4) * 16;
    const int b = blockIdx.y;
    if (tid < 288) sw[tid / 9][tid % 9] = W[tid] * mod[b * 288 + tid];
    for (int pos = tid; pos < 18 * 18; pos += 256) {
        int yy = pos / 18, xx = pos - yy * 18;
        int gy = ty0 + yy - 1, gx = tx0 + xx - 1;
        bool inb = gy >= 0 && gy < 256 && gx >= 0 && gx < 256;
        s[yy][xx] = inb ? x0[((size_t)b << 16) + gy * 256 + gx] : 0.f;
    }
    __syncthreads();
    float v[3][3];
#pragma unroll
    for (int r = 0; r < 3; ++r)
#pragma unroll
        for (int c = 0; c < 3; ++c) v[r][c] = s[ty + r][tx + c];
    float vals[32];
#pragma unroll
    for (int co = 0; co < 32; ++co) {
        float a = 0.f;
#pragma unroll
        for (int r = 0; r < 3; ++r)
#pragma unroll
            for (int c = 0; c < 3; ++c) a = fmaf(v[r][c], sw[co][r * 3 + c], a);
        vals[co] = a;
    }
#pragma unroll
    for (int j = 0; j < 4; ++j) {
        short8 o;
#pragma unroll
        for (int e = 0; e < 8; ++e) o[e] = f2bf(vals[j * 8 + e]);
        *(short8*)&sd[ty][tx][j * 8] = o;
    }
    __syncthreads();
    // dense stores: 1KB contiguous per 64 chunks
    for (int c = tid; c < 1024; c += 256) {
        int row = c >> 6, o = c & 63;
        short8 vv = *(short8*)&sd[row][o >> 2][(o & 3) * 8];
        *(short8*)(y + (((size_t)b * 256 + ty0 + row) * 256 + tx0 + (o >> 2)) * 32 + (o & 3) * 8) = vv;
    }
    // stat partials: thread = (channel, pixel-group), transpose-read from LDS
    {
        const int c = tid & 31, grp = tid >> 5;
        const short* sdf = (const short*)sd;
        float ss = 0.f, ss2 = 0.f;
#pragma unroll
        for (int p = 0; p < 32; ++p) {
            float vv = bf2f(sdf[(grp * 32 + p) * 32 + c]);
            ss += vv; ss2 += vv * vv;
        }
        s_red[grp][c][0] = ss;
        s_red[grp][c][1] = ss2;
    }
    __syncthreads();
    if (tid < 32) {
        float S = 0.f, S2 = 0.f;
#pragma unroll
        for (int g2 = 0; g2 < 8; ++g2) { S += s_red[g2][tid][0]; S2 += s_red[g2][tid][1]; }
        int bucket = blockIdx.x & 7;
        float* sp = (float*)&stats[(size_t)bucket * STST + (size_t)b * 32 + tid];
        atomicAdd(sp, S); atomicAdd(sp + 1, S2);
    }
}

// ---------------- 2x2 maxpool + fused norm/relu + normalized skip writeback -
__global__ __launch_bounds__(256) void maxpool_cl(
    short* __restrict__ in, const float2* __restrict__ st, float invHW,
    short* __restrict__ out, int c8s, int ws, int hs, int total8)
{
    const int C = 8 << c8s;
    __shared__ float2 sst[2048];     // 8 batches x C channels (mu, rsig)
    for (int i = threadIdx.x; i < 8 * C; i += 256) {
        int bb = i / C, c = i % C;
        float sx = 0.f, sy = 0.f;
#pragma unroll
        for (int k = 0; k < 8; ++k) {
            float2 v = st[(size_t)k * STST + (size_t)bb * C + c];
            sx += v.x; sy += v.y;
        }
        float mu = sx * invHW;
        sst[i] = make_float2(mu, rsqrtf(sy * invHW - mu * mu + EPS_IN));
    }
    __syncthreads();
    for (int idx = blockIdx.x * 256 + threadIdx.x; idx < total8; idx += gridDim.x * 256) {
        int c8 = idx & ((1 << c8s) - 1);
        int p = idx >> c8s;
        int x = p & ((1 << ws) - 1);
        int yy = (p >> ws) & ((1 << hs) - 1);
        int b = p >> (ws + hs);
        short* ip = in + (((size_t)b * (2 << hs) + 2 * yy) * (2 << ws) + 2 * x) * C + c8 * 8;
        size_t rs = (size_t)(2 << ws) * C;
        short8 v0 = *(const short8*)ip, v1 = *(const short8*)(ip + C);
        short8 v2 = *(const short8*)(ip + rs), v3 = *(const short8*)(ip + rs + C);
        short8 o, w0, w1, w2, w3;
#pragma unroll
        for (int e = 0; e < 8; ++e) {
            float2 sv = sst[b * C + c8 * 8 + e];
            float n0 = fmaxf(0.f, (bf2f(v0[e]) - sv.x) * sv.y);
            float n1 = fmaxf(0.f, (bf2f(v1[e]) - sv.x) * sv.y);
            float n2 = fmaxf(0.f, (bf2f(v2[e]) - sv.x) * sv.y);
            float n3 = fmaxf(0.f, (bf2f(v3[e]) - sv.x) * sv.y);
            w0[e] = f2bf(n0); w1[e] = f2bf(n1); w2[e] = f2bf(n2); w3[e] = f2bf(n3);
            o[e] = f2bf(fmaxf(fmaxf(n0, n1), fmaxf(n2, n3)));
        }
        *(short8*)ip = w0;
        *(short8*)(ip + C) = w1;
        *(short8*)(ip + rs) = w2;
        *(short8*)(ip + rs + C) = w3;
        *(short8*)(out + (size_t)idx * 8) = o;
    }
}

// ---------------- bilinear 2x upsample + fused norm/relu (u0 source only) ---
__global__ __launch_bounds__(256) void upsample_cl(
    const short* __restrict__ in, const float2* __restrict__ st, float invHW,
    short* __restrict__ out, int c8s, int wsi, int hsi, int total8)
{
    const int C = 8 << c8s;
    const int Win = 1 << wsi, Hin = 1 << hsi;
    __shared__ float2 sst[2048];
    for (int i = threadIdx.x; i < 8 * C; i += 256) {
        int bb = i / C, c = i % C;
        float sx = 0.f, sy = 0.f;
#pragma unroll
        for (int k = 0; k < 8; ++k) {
            float2 v = st[(size_t)k * STST + (size_t)bb * C + c];
            sx += v.x; sy += v.y;
        }
        float mu = sx * invHW;
        sst[i] = make_float2(mu, rsqrtf(sy * invHW - mu * mu + EPS_IN));
    }
    __syncthreads();
    for (int idx = blockIdx.x * 256 + threadIdx.x; idx < total8; idx += gridDim.x * 256) {
        int c8 = idx & ((1 << c8s) - 1);
        int p = idx >> c8s;
        int x = p & (2 * Win - 1);
        int yy = (p >> (wsi + 1)) & (2 * Hin - 1);
        int b = p >> (wsi + 1 + hsi + 1);
        int xk = x >> 1, yk = yy >> 1;
        int xa, xb; float wxa;
        if (x & 1) { xa = xk; xb = (xk + 1 < Win) ? xk + 1 : Win - 1; wxa = 0.75f; }
        else       { xa = (xk > 0) ? xk - 1 : 0; xb = xk; wxa = 0.25f; }
        int ya, yb; float wya;
        if (yy & 1) { ya = yk; yb = (yk + 1 < Hin) ? yk + 1 : Hin - 1; wya = 0.75f; }
        else        { ya = (yk > 0) ? yk - 1 : 0; yb = yk; wya = 0.25f; }
        const short* ib = in + (size_t)b * Hin * Win * C + c8 * 8;
        short8 vaa = *(const short8*)(ib + ((size_t)ya * Win + xa) * C);
        short8 vab = *(const short8*)(ib + ((size_t)ya * Win + xb) * C);
        short8 vba = *(const short8*)(ib + ((size_t)yb * Win + xa) * C);
        short8 vbb = *(const short8*)(ib + ((size_t)yb * Win + xb) * C);
        short8 o;
#pragma unroll
        for (int e = 0; e < 8; ++e) {
            float2 sv = sst[b * C + c8 * 8 + e];
            float aa = fmaxf(0.f, (bf2f(vaa[e]) - sv.x) * sv.y);
            float ab = fmaxf(0.f, (bf2f(vab[e]) - sv.x) * sv.y);
            float ba = fmaxf(0.f, (bf2f(vba[e]) - sv.x) * sv.y);
            float bb = fmaxf(0.f, (bf2f(vbb[e]) - sv.x) * sv.y);
            float r0 = wxa * aa + (1.f - wxa) * ab;
            float r1 = wxa * ba + (1.f - wxa) * bb;
            o[e] = f2bf(wya * r0 + (1.f - wya) * r1);
        }
        *(short8*)(out + (size_t)idx * 8) = o;
    }
}

// ---------------- compose the three 1x1 convs into one 32->1 map ------------
__global__ void eff1x1(const float* __restrict__ w1, const float* __restrict__ b1,
                       const float* __restrict__ w2, const float* __restrict__ b2,
                       const float* __restrict__ w3, const float* __restrict__ b3,
                       float* __restrict__ eff)
{
    int t = threadIdx.x;
    if (t < 32) {
        float s = 0.f;
        for (int k = 0; k < 16; ++k) s += w2[k] * w1[k * 32 + t];
        eff[t] = w3[0] * s;
    }
    if (t == 32) {
        float s = 0.f;
        for (int k = 0; k < 16; ++k) s += w2[k] * b1[k];
        eff[32] = w3[0] * (s + b2[0]) + b3[0];
    }
}

// ---------------- 256-point radix-2 FFT in LDS (one wave) -------------------
__device__ __forceinline__ void fft256(float2* s, int tid, float sign)
{
    __syncthreads();
#pragma unroll
    for (int t = 0; t < 4; ++t) {
        int i = tid + t * 64;
        int r = __brev(i) >> 24;
        if (r > i) { float2 tmp = s[i]; s[i] = s[r]; s[r] = tmp; }
    }
    __syncthreads();
    for (int st = 1; st <= 8; ++st) {
        int m = 1 << st, half = m >> 1;
#pragma unroll
        for (int t = 0; t < 2; ++t) {
            int k = tid + t * 64;
            int g = k >> (st - 1), j = k & (half - 1);
            int i0 = (g << st) + j, i1 = i0 + half;
            float ang = sign * 6.283185307179586f * (float)j / (float)m;
            float sn, cs;
            __sincosf(ang, &sn, &cs);
            float2 a = s[i0], b = s[i1];
            float2 tt = make_float2(b.x * cs - b.y * sn, b.x * sn + b.y * cs);
            s[i0] = make_float2(a.x + tt.x, a.y + tt.y);
            s[i1] = make_float2(a.x - tt.x, a.y - tt.y);
        }
        __syncthreads();
    }
}

// ---------------- fused: norm(u3) + 1x1 chain + residual + row FFT ----------
__global__ __launch_bounds__(64) void final_fft_rows(
    const short* __restrict__ act, const float2* __restrict__ st, float invHW,
    const float* __restrict__ x0, const float* __restrict__ eff,
    float2* __restrict__ cplx)
{
    __shared__ float2 s[256];
    __shared__ float2 sst[32];
    __shared__ float seff[33];
    const int row = blockIdx.x, tid = threadIdx.x;
    const int b = row >> 8, yy = row & 255;
    if (tid < 32) {
        float sx = 0.f, sy = 0.f;
#pragma unroll
        for (int k = 0; k < 8; ++k) {
            float2 v = st[(size_t)k * STST + (size_t)b * 32 + tid];
            sx += v.x; sy += v.y;
        }
        float mu = sx * invHW;
        sst[tid] = make_float2(mu, rsqrtf(sy * invHW - mu * mu + EPS_IN));
    }
    if (tid < 33) seff[tid] = eff[tid];
    __syncthreads();
#pragma unroll
    for (int k = 0; k < 4; ++k) {
        int x = k * 64 + tid;
        const short8* a = (const short8*)(act + (((size_t)b * 256 + yy) * 256 + x) * 32);
        float sacc = seff[32] + x0[((size_t)b << 16) + (yy << 8) + x];
#pragma unroll
        for (int j = 0; j < 4; ++j) {
            short8 v = a[j];
#pragma unroll
            for (int e = 0; e < 8; ++e) {
                float2 sv = sst[j * 8 + e];
                sacc += seff[j * 8 + e] * fmaxf(0.f, (bf2f(v[e]) - sv.x) * sv.y);
            }
        }
        s[x] = make_float2(sacc, 0.f);
    }
    fft256(s, tid, -1.f);
    float2* o = cplx + (size_t)row * 256;
    for (int i = tid; i < 256; i += 64) o[i] = s[i];
}

__global__ __launch_bounds__(64) void fft_cols_combine(float2* __restrict__ data,
                                                       const float* __restrict__ ksp,
                                                       const float* __restrict__ mask)
{
    __shared__ float2 s[256];
    int col = blockIdx.x & 255, b = blockIdx.x >> 8;
    int tid = threadIdx.x;
    float2* base = data + (size_t)b * 65536 + col;
    for (int i = tid; i < 256; i += 64) s[i] = base[(size_t)i * 256];
    fft256(s, tid, -1.f);
    for (int i = tid; i < 256; i += 64) {
        size_t mi = ((size_t)b * 256 + i) * 256 + col;
        float m = mask[mi];
        float2 kp = s[i];
        float kr = ksp[mi * 2], ki = ksp[mi * 2 + 1];
        s[i] = make_float2(m * kr + (1.f - m) * kp.x * (1.f / 256.f),
                           m * ki + (1.f - m) * kp.y * (1.f / 256.f));
    }
    fft256(s, tid, 1.f);
    for (int i = tid; i < 256; i += 64) base[(size_t)i * 256] = s[i];
}

__global__ __launch_bounds__(64) void fft_rows_inv(const float2* __restrict__ data,
                                                   float* __restrict__ out)
{
    __shared__ float2 s[256];
    int row = blockIdx.x, tid = threadIdx.x;
    const float2* p = data + (size_t)row * 256;
    for (int i = tid; i < 256; i += 64) s[i] = p[i];
    fft256(s, tid, 1.f);
    float* o = out + (size_t)row * 256;
    for (int i = tid; i < 256; i += 64) o[i] = s[i].x * (1.f / 256.f);
}

// ---------------------------------------------------------------------------
extern "C" void kernel_launch(void* const* d_in, const int* in_sizes, int n_in,
                              void* d_out, int out_size, void* d_ws, size_t ws_size,
                              hipStream_t stream)
{
    (void)in_sizes; (void)n_in; (void)out_size; (void)ws_size;

    const float* x0 = (const float*)d_in[0];
    const float* ksp = (const float*)d_in[1];
    const float* mask = (const float*)d_in[2];
    const float* mod_d[4] = {(const float*)d_in[3], (const float*)d_in[6],
                             (const float*)d_in[9], (const float*)d_in[12]};
    const float* W_d[4] = {(const float*)d_in[4], (const float*)d_in[7],
                           (const float*)d_in[10], (const float*)d_in[13]};
    const float* mod_lat = (const float*)d_in[15];
    const float* W_lat = (const float*)d_in[16];
    const float* mod_u[4] = {(const float*)d_in[18], (const float*)d_in[21],
                             (const float*)d_in[24], (const float*)d_in[27]};
    const float* W_u[4] = {(const float*)d_in[19], (const float*)d_in[22],
                           (const float*)d_in[25], (const float*)d_in[28]};
    const float* w_c1 = (const float*)d_in[30];
    const float* b_c1 = (const float*)d_in[31];
    const float* w_c2 = (const float*)d_in[32];
    const float* b_c2 = (const float*)d_in[33];
    const float* w_c3 = (const float*)d_in[34];
    const float* b_c3 = (const float*)d_in[35];

    // ---- workspace layout (CL bf16 activations), ~164 MB
    short* sA  = (short*)d_ws;          // 16,777,216
    short* sB  = sA + 16777216;         // 16,777,216
    short* sk0 = sB + 16777216;         // 16,777,216 (8,256,256,32)
    short* sk1 = sk0 + 16777216;        //  8,388,608 (8,128,128,64)
    short* sk2 = sk1 + 8388608;         //  4,194,304 (8,64,64,128)
    short* sk3 = sk2 + 4194304;         //  2,097,152 (8,32,32,256)
    short* wm_d1 = sk3 + 2097152;       //    147,456
    short* wm_d2 = wm_d1 + 147456;      //    589,824
    short* wm_d3 = wm_d2 + 589824;      //  2,359,296
    short* wm_lat = wm_d3 + 2359296;    //  4,718,592
    short* wm_u0 = wm_lat + 4718592;    //  4,718,592
    short* wm_u1 = wm_u0 + 4718592;     //  1,179,648
    short* wm_u2 = wm_u1 + 1179648;     //    294,912
    short* wm_u3 = wm_u2 + 294912;      //    147,456
    float2* cplx = (float2*)(wm_u3 + 147456);  // 524,288 float2
    float2* stA = cplx + 524288;               // 8 buckets x 7,936 float2
    float* eff = (float*)(stA + 8 * STST);     // 64

    // per-layer stat slices (bucket 0 base; buckets at +k*STST)
    float2* st_d0 = stA + 0;
    float2* st_d1 = stA + 256;
    float2* st_d2 = stA + 768;
    float2* st_d3 = stA + 1792;
    float2* st_lat = stA + 3840;
    float2* st_u0 = stA + 5888;
    float2* st_u1 = stA + 6912;
    float2* st_u2 = stA + 7424;
    float2* st_u3 = stA + 7680;

    const float i64k = 1.f / 65536.f, i16k = 1.f / 16384.f, i4k = 1.f / 4096.f,
                i1k = 1.f / 1024.f, i256 = 1.f / 256.f;

    dim3 blk(256);

    zero_f<<<496, blk, 0, stream>>>((float*)stA, 8 * STST * 2);
    eff1x1<<<1, 64, 0, stream>>>(w_c1, b_c1, w_c2, b_c2, w_c3, b_c3, eff);

    // ---- all modded weights, one launch
    WmJobs jobs;
    const float* Wl[8]  = {W_d[1], W_d[2], W_d[3], W_lat, W_u[0], W_u[1], W_u[2], W_u[3]};
    const float* Ml[8]  = {mod_d[1], mod_d[2], mod_d[3], mod_lat, mod_u[0], mod_u[1], mod_u[2], mod_u[3]};
    short* WMl[8] = {wm_d1, wm_d2, wm_d3, wm_lat, wm_u0, wm_u1, wm_u2, wm_u3};
    int Col[8] = {64, 128, 256, 256, 128, 64, 32, 32};
    int Cil[8] = {32, 64, 128, 256, 512, 256, 128, 64};
    jobs.cum[0] = 0;
    for (int l = 0; l < 8; ++l) {
        jobs.W[l] = Wl[l]; jobs.mod[l] = Ml[l]; jobs.wm[l] = WMl[l];
        jobs.Co[l] = Col[l]; jobs.Ci[l] = Cil[l];
        jobs.cum[l + 1] = jobs.cum[l] + 8 * Col[l] * Cil[l];
    }
    make_wm_all<<<(jobs.cum[8] + 255) / 256, blk, 0, stream>>>(jobs);

    // ---- down path
    conv_d0_cl<<<dim3(256, 8), blk, 0, stream>>>(x0, W_d[0], mod_d[0], sk0, st_d0);
    maxpool_cl<<<2048, blk, 0, stream>>>(sk0, st_d0, i64k, sA, 2, 7, 7, 524288);

    conv3x3_cl<4, 4, false><<<512, blk, 0, stream>>>(sA, 32, sA, stA, 0.f, wm_d1, sk1, st_d1, 32, 64, 128, 128);
    maxpool_cl<<<1024, blk, 0, stream>>>(sk1, st_d1, i16k, sA, 3, 6, 6, 262144);

    conv3x3_cl<2, 4, false><<<512, blk, 0, stream>>>(sA, 64, sA, stA, 0.f, wm_d2, sk2, st_d2, 64, 128, 64, 64);
    maxpool_cl<<<512, blk, 0, stream>>>(sk2, st_d2, i4k, sA, 4, 5, 5, 131072);

    conv3x3_cl<2, 2, false><<<512, blk, 0, stream>>>(sA, 128, sA, stA, 0.f, wm_d3, sk3, st_d3, 128, 256, 32, 32);
    maxpool_cl<<<256, blk, 0, stream>>>(sk3, st_d3, i1k, sA, 5, 4, 4, 65536);

    conv3x3_cl<2, 1, false><<<256, blk, 0, stream>>>(sA, 256, sA, stA, 0.f, wm_lat, sB, st_lat, 256, 256, 16, 16);

    // ---- up path
    upsample_cl<<<1024, blk, 0, stream>>>(sB, st_lat, i256, sA, 5, 4, 4, 262144);
    conv3x3_cl<2, 1, false><<<512, blk, 0, stream>>>(sA, 256, sk3, stA, 0.f, wm_u0, sB, st_u0, 512, 128, 32, 32);
    conv3x3_cl<2, 2, true><<<512, blk, 0, stream>>>(sB, 128, sk2, st_u0, i1k, wm_u1, sA, st_u1, 256, 64, 64, 64);
    conv3x3_cl<4, 2, true><<<512, blk, 0, stream>>>(sA, 64, sk1, st_u1, i4k, wm_u2, sB, st_u2, 128, 32, 128, 128);
    conv3x3_cl<4, 2, true><<<2048, blk, 0, stream>>>(sB, 32, sk0, st_u2, i16k, wm_u3, sA, st_u3, 64, 32, 256, 256);

    // ---- fused norm(u3) + 1x1 chain + residual + row FFT
    final_fft_rows<<<2048, 64, 0, stream>>>(sA, st_u3, i64k, x0, eff, cplx);

    // ---- FFT data consistency
    fft_cols_combine<<<2048, 64, 0, stream>>>(cplx, ksp, mask);
    fft_rows_inv<<<2048, 64, 0, stream>>>(cplx, (float*)d_out);
}